// Round 27
// baseline (452.821 us; speedup 1.0000x reference)
//
#include <hip/hip_runtime.h>
#include <hip/hip_bf16.h>

typedef __hip_bfloat16 bf16;
typedef __attribute__((ext_vector_type(8))) short short8v;
typedef __attribute__((ext_vector_type(4))) float f32x4;

#define DEV static __device__ __forceinline__

DEV float b2f(bf16 h){ return __bfloat162float(h); }
DEV float us2f(unsigned short u){ unsigned v=((unsigned)u)<<16; float f; __builtin_memcpy(&f,&v,4); return f; }
DEV short f2bs(float f){ bf16 h=__float2bfloat16(f); short s; __builtin_memcpy(&s,&h,2); return s; }
DEV unsigned pack2(float a, float b){ return ((unsigned)(unsigned short)f2bs(b)<<16)|(unsigned short)f2bs(a); }
DEV float lrelu(float x){ return x >= 0.f ? x : 0.1f*x; }
DEV float geluf(float x){ return 0.5f*x*(1.f + erff(x*0.70710678118654752440f)); }
DEV float sigmoidf(float x){ return 1.f/(1.f + expf(-x)); }

// B=4, C=64, H=W=256, HW=65536, WS=8, N=1024 windows/batch, embed=4096

// ---------------- K0b v2: convert small weights to f32 wbuf; self-detect dtype; block0 writes flag ----------------
struct CvtArgs { const void* src[31]; int sz[31]; int off[31]; };
__global__ __launch_bounds__(256) void k_cvt(CvtArgs a, const void* x, int* flag, float* wbuf){
  __shared__ int cnt;
  if(threadIdx.x==0) cnt=0;
  __syncthreads();
  const unsigned short* up=(const unsigned short*)x;
  int c=0;
  for(int k=0;k<16;k++){
    unsigned short u=up[(threadIdx.x*16+k)*2];
    if(((u>>7)&0xFF)==0xFF) c++;
  }
  atomicAdd(&cnt,c);
  __syncthreads();
  int isf32 = (cnt>0);
  if(blockIdx.x==0 && threadIdx.x==0) flag[0]=isf32;
  int t=blockIdx.x; int n=a.sz[t]; const void* s=a.src[t]; float* d=wbuf+a.off[t];
  if(isf32){
    const float* sp=(const float*)s;
    for(int i=threadIdx.x;i<n;i+=256) d[i]=sp[i];
  } else {
    const bf16* sp=(const bf16*)s;
    for(int i=threadIdx.x;i<n;i+=256) d[i]=b2f(sp[i]);
  }
}

// ---------------- K_PREP: merged w2b6 (blocks 0-31) + qkcomp (32-47) + wcomp (48) ----------------
__global__ __launch_bounds__(256) void k_prep(
    const float* __restrict__ wo, const float* __restrict__ wfi,
    const float* __restrict__ wfo, const float* __restrict__ wv,
    const float* __restrict__ wq, const float* __restrict__ wk,
    const float* __restrict__ bq, const float* __restrict__ bk,
    const float* __restrict__ W_in, const float* __restrict__ b_in,
    const float* __restrict__ Wc, const float* __restrict__ bc,
    const float* __restrict__ bv,
    short* __restrict__ Wob, short* __restrict__ Wfib, short* __restrict__ Wfob,
    short* __restrict__ Wvb, short* __restrict__ MtB,
    float* __restrict__ cvec, float* __restrict__ cconst,
    float* __restrict__ Wa, float* __restrict__ ba,
    float* __restrict__ Wb2, float* __restrict__ bb2){
  int bid=blockIdx.x, tid=threadIdx.x;
  if(bid<32){
    int i=bid*256+tid;
    if(i<4096){ Wob[i]=f2bs(wo[i]); Wfob[i]=f2bs(wfo[i]); Wvb[i]=f2bs(wv[i]); }
    if(i<8192) Wfib[i]=f2bs(wfi[i]);
  } else if(bid<48){
    int idx=(bid-32)*256+tid;
    if(idx<4096){
      int cp=idx>>6, c=idx&63;
      float s=0.f;
      for(int o=0;o<64;o++) s+=wq[o*64+c]*wk[o*64+cp];
      MtB[cp*64+c]=f2bs(s);
    }
    if(bid==32){
      if(tid<64){
        float s=0.f;
        for(int o=0;o<64;o++) s+=bq[o]*wk[o*64+tid];
        cvec[tid]=s;
      } else if(tid==64){
        float s=0.f;
        for(int o=0;o<64;o++) s+=bq[o]*bk[o];
        cconst[0]=s;
      }
    }
  } else {
    #pragma unroll
    for(int ii=0;ii<4;ii++){
      int idx=tid+ii*256;
      int i=idx>>6, c=idx&63;
      float sa=0.f, sb=0.f;
      for(int k=0;k<64;k++){
        float wv2=wv[k*64+c];
        sa+=W_in[i*64+k]*wv2;
        sb+=Wc[i*64+k]*wv2;
      }
      Wa[idx]=sa; Wb2[idx]=sb;
    }
    if(tid<16){
      float sa=0.f, sb=0.f;
      for(int k=0;k<64;k++){ sa+=W_in[tid*64+k]*bv[k]; sb+=Wc[tid*64+k]*bv[k]; }
      ba[tid]=sa+b_in[tid]; bb2[tid]=sb+bc[tid];
    }
  }
}

// ---------------- K1 v2: conv_v MFMA -> vw, PLUS masked token-major xwb ----------------
__global__ __launch_bounds__(256) void k_convv_mf(
    const void* __restrict__ in, const int* __restrict__ fl,
    const short* __restrict__ Wvb, const float* __restrict__ bv,
    const float* __restrict__ mbin, const float* __restrict__ m0T, const float* __restrict__ m1T,
    unsigned short* __restrict__ vw, unsigned short* __restrict__ xwb){
  __shared__ float Xf[64*66];
  int tid=threadIdx.x;
  int g0=blockIdx.x*64; int b=g0>>16, p0=g0&65535;
  int c=tid>>2, q=tid&3;
  size_t base=(((size_t)(b*64+c))<<16) + p0;
  if(fl[0]){
    const float* ip=(const float*)in + base;
    #pragma unroll
    for(int j=0;j<4;j++){
      int po=q*16+j*4;
      float4 xv=*(const float4*)(ip+po);
      *(float2*)&Xf[c*66+po]=make_float2(xv.x,xv.y);
      *(float2*)&Xf[c*66+po+2]=make_float2(xv.z,xv.w);
    }
  } else {
    const unsigned short* ip=(const unsigned short*)in + base;
    #pragma unroll
    for(int j=0;j<4;j++){
      int po=q*16+j*4;
      uint2 u=*(const uint2*)(ip+po);
      *(float2*)&Xf[c*66+po]=make_float2(us2f(u.x&0xffff),us2f(u.x>>16));
      *(float2*)&Xf[c*66+po+2]=make_float2(us2f(u.y&0xffff),us2f(u.y>>16));
    }
  }
  __syncthreads();
  int lane=tid&63, wid=tid>>6;
  int lr=lane&15, lg=lane>>4;
  int pix0=wid*16;
  short8v bfrag[2];
  #pragma unroll
  for(int ks=0;ks<2;ks++){
    short8v v;
    #pragma unroll
    for(int i=0;i<8;i++) v[i]=f2bs(Xf[(ks*32+lg*8+i)*66 + pix0+lr]);
    bfrag[ks]=v;
  }
  int y=p0>>8;
  int xx=(p0&255)+pix0+lr;
  int n=((y>>3)<<5)|(xx>>3), tok=((y&7)<<3)|(xx&7);
  unsigned short* wp=vw + (((size_t)(b*1024+n))<<12) + tok;
  #pragma unroll
  for(int nt=0;nt<4;nt++){
    f32x4 acc;
    #pragma unroll
    for(int r=0;r<4;r++) acc[r]=bv[nt*16+lg*4+r];
    #pragma unroll
    for(int ks=0;ks<2;ks++){
      short8v afrag=*(const short8v*)(Wvb + (nt*16+lr)*64 + ks*32 + lg*8);
      acc=__builtin_amdgcn_mfma_f32_16x16x32_bf16(afrag,bfrag[ks],acc,0,0,0);
    }
    #pragma unroll
    for(int r=0;r<4;r++){
      int m=nt*16+lg*4+r;
      wp[(size_t)m*64]=(unsigned short)f2bs(acc[r]);
    }
  }
  int nw0=((y>>3)<<5) | ((p0&255)>>3);
  int trow=(y&7)*8;
  #pragma unroll
  for(int k2=0;k2<2;k2++){
    int task=tid+k2*256;
    int w=task>>6, rem=task&63, j=rem>>3, cg=rem&7;
    int nn=nw0+w;
    const float* mT=(mbin[b*1024+nn]>0.5f)? m1T : m0T;
    int tk=trow+j;
    int pixl=w*8+j;
    unsigned short ov[8];
    #pragma unroll
    for(int i=0;i<8;i++){
      int ch=cg*8+i;
      ov[i]=(unsigned short)f2bs(Xf[ch*66+pixl]*mT[ch*64+tk]);
    }
    uint4 o;
    o.x=((unsigned)ov[1]<<16)|ov[0]; o.y=((unsigned)ov[3]<<16)|ov[2];
    o.z=((unsigned)ov[5]<<16)|ov[4]; o.w=((unsigned)ov[7]<<16)|ov[6];
    *(uint4*)(xwb + (((size_t)(b*1024+nn))<<12) + tk*64 + cg*8)=o;
  }
}

// ---------------- K_GLF v3: fused Wo-GEMM + residual + LN -> x1b, then ffn_in GEMM -> E ----------------
// Residual loads issued AFTER staging retires (post-bfrag), folded into acc init.
__global__ __launch_bounds__(256) void k_gemm_lnfi(
    const unsigned short* __restrict__ in,
    const short* __restrict__ Wb, const float* __restrict__ bias,
    const void* __restrict__ basex,
    const float* __restrict__ lnw, const float* __restrict__ lnb,
    unsigned short* __restrict__ xout,
    const short* __restrict__ Wfib,
    unsigned short* __restrict__ E,
    const int* __restrict__ fl){
  __shared__ short Ain[64*72];
  int tid=threadIdx.x;
  int g0=blockIdx.x*64; int b=g0>>16, p0=g0&65535;
  int c=tid>>2, q=tid&3;
  {
    const unsigned short* ip=in + (((size_t)(b*64+c))<<16) + p0;
    #pragma unroll
    for(int j=0;j<4;j++){
      int po=q*16+j*4;
      uint2 u=*(const uint2*)(ip+po);
      Ain[(po+0)*72+c]=(short)(u.x&0xffff); Ain[(po+1)*72+c]=(short)(u.x>>16);
      Ain[(po+2)*72+c]=(short)(u.y&0xffff); Ain[(po+3)*72+c]=(short)(u.y>>16);
    }
  }
  __syncthreads();
  int lane=tid&63, wid=tid>>6;
  int lr=lane&15, lg=lane>>4;
  int pix0=wid*16;
  short8v bfrag[2];
  #pragma unroll
  for(int ks=0;ks<2;ks++) bfrag[ks]=*(const short8v*)&Ain[(pix0+lr)*72 + ks*32 + lg*8];
  __syncthreads();   // all waves done reading Ain before it is overwritten below
  int pix=p0+pix0+lr;
  // residual loads (bias folded) issued here: staging temporaries are dead,
  // loads overlap the Wo MFMAs below (L3-warm x).
  float rl[16];
  if(fl[0]){
    const float* xp=(const float*)basex;
    #pragma unroll
    for(int nt=0;nt<4;nt++)
      #pragma unroll
      for(int r=0;r<4;r++){
        int m=nt*16+lg*4+r;
        rl[nt*4+r]=bias[m]+xp[(((size_t)(b*64+m))<<16)+pix];
      }
  } else {
    const unsigned short* xp=(const unsigned short*)basex;
    #pragma unroll
    for(int nt=0;nt<4;nt++)
      #pragma unroll
      for(int r=0;r<4;r++){
        int m=nt*16+lg*4+r;
        rl[nt*4+r]=bias[m]+us2f(xp[(((size_t)(b*64+m))<<16)+pix]);
      }
  }
  #pragma unroll
  for(int nt=0;nt<4;nt++){
    f32x4 acc;
    #pragma unroll
    for(int r=0;r<4;r++) acc[r]=rl[nt*4+r];
    #pragma unroll
    for(int ks=0;ks<2;ks++){
      short8v afrag=*(const short8v*)(Wb + (nt*16+lr)*64 + ks*32 + lg*8);
      acc=__builtin_amdgcn_mfma_f32_16x16x32_bf16(afrag,bfrag[ks],acc,0,0,0);
    }
    #pragma unroll
    for(int r=0;r<4;r++) rl[nt*4+r]=acc[r];
  }
  float s=0.f;
  #pragma unroll
  for(int i=0;i<16;i++) s+=rl[i];
  s+=__shfl_xor(s,16); s+=__shfl_xor(s,32);
  float mean=s*(1.f/64.f);
  float qv=0.f;
  #pragma unroll
  for(int i=0;i<16;i++){ float d=rl[i]-mean; qv+=d*d; }
  qv+=__shfl_xor(qv,16); qv+=__shfl_xor(qv,32);
  float inv=1.f/sqrtf(qv*(1.f/64.f)+1e-6f);
  // write x1b (bf16) and the same bits into the LDS tile (token-major rows)
  #pragma unroll
  for(int nt=0;nt<4;nt++){
    unsigned short sb[4];
    #pragma unroll
    for(int r=0;r<4;r++){
      int m=nt*16+lg*4+r;
      unsigned short v=(unsigned short)f2bs(lnw[m]*((rl[nt*4+r]-mean)*inv)+lnb[m]);
      sb[r]=v;
      xout[(((size_t)(b*64+m))<<16)+pix]=v;
    }
    uint2 w;
    w.x=((unsigned)sb[1]<<16)|sb[0];
    w.y=((unsigned)sb[3]<<16)|sb[2];
    *(uint2*)&Ain[(pix0+lr)*72 + nt*16+lg*4]=w;
  }
  __syncthreads();
  // ffn_in GEMM: 128 output channels from LN'd tile
  short8v bfrag2[2];
  #pragma unroll
  for(int ks=0;ks<2;ks++) bfrag2[ks]=*(const short8v*)&Ain[(pix0+lr)*72 + ks*32 + lg*8];
  #pragma unroll
  for(int nt=0;nt<8;nt++){
    f32x4 acc={0.f,0.f,0.f,0.f};
    #pragma unroll
    for(int ks=0;ks<2;ks++){
      short8v afrag=*(const short8v*)(Wfib + (nt*16+lr)*64 + ks*32 + lg*8);
      acc=__builtin_amdgcn_mfma_f32_16x16x32_bf16(afrag,bfrag2[ks],acc,0,0,0);
    }
    #pragma unroll
    for(int r=0;r<4;r++){
      int m=nt*16+lg*4+r;
      E[(((size_t)(b*128+m))<<16) + pix]=(unsigned short)f2bs(acc[r]);
    }
  }
}

// ---------------- K_GL v3: MFMA GEMM (64 och) + residual + LN; residual loads post-bfrag ----------------
__global__ __launch_bounds__(256) void k_gemm_ln(
    const unsigned short* __restrict__ in,
    const short* __restrict__ Wb, const float* __restrict__ bias, int has_bias,
    const void* __restrict__ basex,
    const float* __restrict__ lnw, const float* __restrict__ lnb,
    void* __restrict__ out,
    const int* __restrict__ fl, int base_mode, int out_mode){
  __shared__ short Ain[64*72];
  int tid=threadIdx.x;
  int g0=blockIdx.x*64; int b=g0>>16, p0=g0&65535;
  int c=tid>>2, q=tid&3;
  {
    const unsigned short* ip=in + (((size_t)(b*64+c))<<16) + p0;
    #pragma unroll
    for(int j=0;j<4;j++){
      int po=q*16+j*4;
      uint2 u=*(const uint2*)(ip+po);
      Ain[(po+0)*72+c]=(short)(u.x&0xffff); Ain[(po+1)*72+c]=(short)(u.x>>16);
      Ain[(po+2)*72+c]=(short)(u.y&0xffff); Ain[(po+3)*72+c]=(short)(u.y>>16);
    }
  }
  __syncthreads();
  int lane=tid&63, wid=tid>>6;
  int lr=lane&15, lg=lane>>4;
  int pix0=wid*16;
  short8v bfrag[2];
  #pragma unroll
  for(int ks=0;ks<2;ks++) bfrag[ks]=*(const short8v*)&Ain[(pix0+lr)*72 + ks*32 + lg*8];
  int pix=p0+pix0+lr;
  float rl[16];
  bool bf32 = (base_mode==1) || (base_mode==0 && fl[0]);
  if(bf32){
    const float* xp=(const float*)basex;
    #pragma unroll
    for(int nt=0;nt<4;nt++)
      #pragma unroll
      for(int r=0;r<4;r++){
        int m=nt*16+lg*4+r;
        rl[nt*4+r]=(has_bias? bias[m]:0.f)+xp[(((size_t)(b*64+m))<<16)+pix];
      }
  } else {
    const unsigned short* xp=(const unsigned short*)basex;
    #pragma unroll
    for(int nt=0;nt<4;nt++)
      #pragma unroll
      for(int r=0;r<4;r++){
        int m=nt*16+lg*4+r;
        rl[nt*4+r]=(has_bias? bias[m]:0.f)+us2f(xp[(((size_t)(b*64+m))<<16)+pix]);
      }
  }
  #pragma unroll
  for(int nt=0;nt<4;nt++){
    f32x4 acc;
    #pragma unroll
    for(int r=0;r<4;r++) acc[r]=rl[nt*4+r];
    #pragma unroll
    for(int ks=0;ks<2;ks++){
      short8v afrag=*(const short8v*)(Wb + (nt*16+lr)*64 + ks*32 + lg*8);
      acc=__builtin_amdgcn_mfma_f32_16x16x32_bf16(afrag,bfrag[ks],acc,0,0,0);
    }
    #pragma unroll
    for(int r=0;r<4;r++) rl[nt*4+r]=acc[r];
  }
  float s=0.f;
  #pragma unroll
  for(int i=0;i<16;i++) s+=rl[i];
  s+=__shfl_xor(s,16); s+=__shfl_xor(s,32);
  float mean=s*(1.f/64.f);
  float qv=0.f;
  #pragma unroll
  for(int i=0;i<16;i++){ float d=rl[i]-mean; qv+=d*d; }
  qv+=__shfl_xor(qv,16); qv+=__shfl_xor(qv,32);
  float inv=1.f/sqrtf(qv*(1.f/64.f)+1e-6f);
  bool of32 = (out_mode==1) || (out_mode==0 && fl[0]);
  if(of32){
    float* op=(float*)out;
    #pragma unroll
    for(int nt=0;nt<4;nt++)
      #pragma unroll
      for(int r=0;r<4;r++){
        int m=nt*16+lg*4+r;
        op[(((size_t)(b*64+m))<<16)+pix]=lnw[m]*((rl[nt*4+r]-mean)*inv)+lnb[m];
      }
  } else {
    unsigned short* op=(unsigned short*)out;
    #pragma unroll
    for(int nt=0;nt<4;nt++)
      #pragma unroll
      for(int r=0;r<4;r++){
        int m=nt*16+lg*4+r;
        op[(((size_t)(b*64+m))<<16)+pix]=(unsigned short)f2bs(lnw[m]*((rl[nt*4+r]-mean)*inv)+lnb[m]);
      }
  }
}

// ---------------- K2: route from x with composed weights (2 pix/thread, f32) ----------------
__global__ __launch_bounds__(256) void k_route(const void* __restrict__ x, const int* __restrict__ fl,
    const float* __restrict__ Wa, const float* __restrict__ ba,
    const float* __restrict__ Wb2, const float* __restrict__ bb2,
    const float* __restrict__ lnw, const float* __restrict__ lnb,
    float* __restrict__ x_, float* __restrict__ xm, float* __restrict__ capart){
  __shared__ float wA[1024], wB[1024], sba[16], sbb[16], slw[16], slb[16];
  __shared__ float sred[4][16];
  int tid=threadIdx.x;
  for(int i=tid;i<1024;i+=256){ wA[i]=Wa[i]; wB[i]=Wb2[i]; }
  if(tid<16){ sba[tid]=ba[tid]; sbb[tid]=bb2[tid]; slw[tid]=lnw[tid]; slb[tid]=lnb[tid]; }
  __syncthreads();
  int g=blockIdx.x*512+tid*2; int b=g>>16, p=g&65535;
  float2 aA[16], aB[16];
  #pragma unroll
  for(int i=0;i<16;i++){ aA[i]=make_float2(sba[i],sba[i]); aB[i]=make_float2(sbb[i],sbb[i]); }
  size_t base=(((size_t)b*64)<<16)+p;
  if(fl[0]){
    const float* vp=(const float*)x+base;
    for(int c=0;c<64;c++){
      float2 vv=*(const float2*)(vp+(((size_t)c)<<16));
      #pragma unroll
      for(int i=0;i<16;i++){
        float wa=wA[(i<<6)+c], wb=wB[(i<<6)+c];
        aA[i].x+=wa*vv.x; aA[i].y+=wa*vv.y;
        aB[i].x+=wb*vv.x; aB[i].y+=wb*vv.y;
      }
    }
  } else {
    const unsigned short* vp=(const unsigned short*)x+base;
    for(int c=0;c<64;c++){
      unsigned u=*(const unsigned*)(vp+(((size_t)c)<<16));
      float v0=us2f(u&0xffff), v1=us2f(u>>16);
      #pragma unroll
      for(int i=0;i<16;i++){
        float wa=wA[(i<<6)+c], wb=wB[(i<<6)+c];
        aA[i].x+=wa*v0; aA[i].y+=wa*v1;
        aB[i].x+=wb*v0; aB[i].y+=wb*v1;
      }
    }
  }
  float s0=0.f,s1=0.f;
  #pragma unroll
  for(int i=0;i<16;i++){ aA[i].x=lrelu(aA[i].x); aA[i].y=lrelu(aA[i].y); s0+=aA[i].x; s1+=aA[i].y; }
  float2 xmst; xmst.x=s0*(1.f/16.f); xmst.y=s1*(1.f/16.f);
  *(float2*)(xm+g)=xmst;
  float u0=0.f,u1=0.f;
  #pragma unroll
  for(int i=0;i<16;i++){ u0+=aB[i].x; u1+=aB[i].y; }
  u0*=(1.f/16.f); u1*=(1.f/16.f);
  float q0=0.f,q1=0.f;
  #pragma unroll
  for(int i=0;i<16;i++){ float d0=aB[i].x-u0, d1=aB[i].y-u1; q0+=d0*d0; q1+=d1*d1; }
  q0*=(1.f/16.f); q1*=(1.f/16.f);
  float i0=1.f/sqrtf(q0+1e-6f), i1=1.f/sqrtf(q1+1e-6f);
  float red[16];
  float* xp=x_+(((size_t)b*16)<<16)+p;
  #pragma unroll
  for(int i=0;i<16;i++){
    float xv0=lrelu(slw[i]*((aB[i].x-u0)*i0)+slb[i]);
    float xv1=lrelu(slw[i]*((aB[i].y-u1)*i1)+slb[i]);
    float2 st; st.x=xv0; st.y=xv1;
    *(float2*)(xp+(((size_t)i)<<16))=st;
    red[i]=xv0+xv1;
  }
  int lane=tid&63, wid=tid>>6;
  #pragma unroll
  for(int i=0;i<16;i++){
    float val=red[i];
    for(int m=32;m>0;m>>=1) val+=__shfl_xor(val,m);
    if(lane==0) sred[wid][i]=val;
  }
  __syncthreads();
  if(tid<16) capart[blockIdx.x*16+tid]=sred[0][tid]+sred[1][tid]+sred[2][tid]+sred[3][tid];
}

// ---------------- K3: sa = sigmoid(conv3x3(x_)) -> window-major bf16 ----------------
__global__ __launch_bounds__(256) void k_sa(const float* __restrict__ x_,
    const float* __restrict__ Wsa, const float* __restrict__ bsa, unsigned short* __restrict__ sa_w){
  __shared__ float w[144]; __shared__ float bb;
  int tid=threadIdx.x;
  if(tid<144) w[tid]=Wsa[tid];
  if(tid==0) bb=bsa[0];
  __syncthreads();
  int pix=blockIdx.x*256+tid; int b=pix>>16, p=pix&65535;
  int y=p>>8, xx=p&255;
  float acc=bb;
  #pragma unroll
  for(int i=0;i<16;i++){
    const float* pl=x_+(((size_t)(b*16+i))<<16);
    #pragma unroll
    for(int ky=0;ky<3;ky++){
      int yy=y+ky-1;
      if((unsigned)yy<256u){
        #pragma unroll
        for(int kx=0;kx<3;kx++){
          int x2=xx+kx-1;
          if((unsigned)x2<256u) acc+=pl[(yy<<8)+x2]*w[i*9+ky*3+kx];
        }
      }
    }
  }
  int n=((y>>3)<<5)|(xx>>3), tok=((y&7)<<3)|(xx&7);
  sa_w[(((size_t)(b<<10)+n)<<6)+tok]=(unsigned short)f2bs(sigmoidf(acc));
}

// ---------------- K_VH: merged per-window variance (blocks 0-1023) + Wm1 rowsums (1024-1535) ----------------
__global__ __launch_bounds__(256) void k_varhvec(const float* __restrict__ xm, float* __restrict__ var,
    const void* __restrict__ Wm1, const float* __restrict__ bm1,
    float* __restrict__ h0, float* __restrict__ h1, const int* __restrict__ fl){
  int bid=blockIdx.x, tid=threadIdx.x;
  int w=tid>>6, l=tid&63;
  if(bid<1024){
    int blk=bid*4+w;
    int b=blk>>10, n=blk&1023;
    int pix=((n>>5)<<11) + ((n&31)<<3) + ((l>>3)<<8) + (l&7);
    float val=xm[(b<<16)+pix];
    float s=val;
    for(int m=32;m>0;m>>=1) s+=__shfl_xor(s,m);
    float mean=s*(1.f/64.f);
    float d=val-mean; float q=d*d;
    for(int m=32;m>0;m>>=1) q+=__shfl_xor(q,m);
    if(l==0) var[blk]=q*(1.f/63.f);
  } else {
    int j=(bid-1024)*4+w;
    float s=0.f;
    if(fl[0]){
      const float* row=(const float*)Wm1+((size_t)j<<12);
      for(int k=l;k<4096;k+=64) s+=row[k];
    } else {
      const bf16* row=(const bf16*)Wm1+((size_t)j<<12);
      for(int k=l;k<4096;k+=64) s+=b2f(row[k]);
    }
    for(int m=32;m>0;m>>=1) s+=__shfl_xor(s,m);
    if(l==0){ float bb=bm1[j]; h0[j]=lrelu(bb); h1[j]=lrelu(bb+s); }
  }
}

// ---------------- K_RMC: merged rank (0-15) + mask (16-1039, 4 rows/block) + ca (1040-1043) ----------------
__global__ __launch_bounds__(256) void k_rankmaskca(
    const float* __restrict__ var, float* __restrict__ mbin,
    const void* __restrict__ Wm2, const float* __restrict__ bm2,
    const float* __restrict__ h0, const float* __restrict__ h1,
    float* __restrict__ m0, float* __restrict__ m1,
    float* __restrict__ m0T, float* __restrict__ m1T,
    const float* __restrict__ capart, const float* __restrict__ Wca,
    const float* __restrict__ bca, float* __restrict__ ca,
    const int* __restrict__ fl){
  __shared__ float va[1024];
  __shared__ float cm[16];
  int bid=blockIdx.x, tid=threadIdx.x;
  if(bid<16){
    int b=bid>>2, seg=bid&3;
    for(int i=tid;i<1024;i+=256) va[i]=var[(b<<10)+i];
    __syncthreads();
    int n=seg*256+tid;
    float vn=va[n]; int r=0;
    for(int m=0;m<1024;m++){ float vm=va[m]; r += (vm<vn) || (vm==vn && m<n); }
    mbin[(b<<10)+n] = (r<512)?0.f:1.f;
  } else if(bid<1040){
    int w=tid>>6, l=tid&63;
    int e=(bid-16)*4+w;
    float p0=0.f,p1=0.f;
    if(fl[0]){
      const float* row=(const float*)Wm2+((size_t)e<<11);
      for(int j=l;j<2048;j+=64){ float wv=row[j]; p0+=wv*h0[j]; p1+=wv*h1[j]; }
    } else {
      const bf16* row=(const bf16*)Wm2+((size_t)e<<11);
      for(int j=l;j<2048;j+=64){ float wv=b2f(row[j]); p0+=wv*h0[j]; p1+=wv*h1[j]; }
    }
    for(int m=32;m>0;m>>=1){ p0+=__shfl_xor(p0,m); p1+=__shfl_xor(p1,m); }
    if(l==0){
      float bb=bm2[e]; float v0=p0+bb, v1=p1+bb;
      m0[e]=v0; m1[e]=v1;
      int te=(e&63)*64+(e>>6);
      m0T[te]=v0; m1T[te]=v1;
    }
  } else {
    int b=bid-1040;
    if(tid<16){
      float s=0.f;
      for(int blk=0;blk<128;blk++) s+=capart[((b*128)+blk)*16+tid];
      cm[tid]=s*(1.f/65536.f);
    }
    __syncthreads();
    if(tid<64){
      float a=bca[tid];
      #pragma unroll
      for(int i=0;i<16;i++) a+=Wca[(tid<<4)+i]*cm[i];
      ca[(b<<6)+tid]=sigmoidf(a);
    }
  }
}

// ---------------- K9 v7: attention; in-place softmax (VGPR trim) + setprio around MFMA ----------------
#define STR 72
#define STRF 65
__global__ __launch_bounds__(256) void k_attn_mfma(
    const unsigned short* __restrict__ xwb, const unsigned short* __restrict__ vw,
    const unsigned short* __restrict__ sa_w, const float* __restrict__ mbin,
    const float* __restrict__ m0T, const float* __restrict__ m1T,
    const short* __restrict__ MtB, const float* __restrict__ cvec, const float* __restrict__ cconst,
    unsigned short* __restrict__ img){
  __shared__ __align__(16) char uf[16640];   // sU (bf16 u/probs) U sF (f32 [64][65])
  __shared__ short sV1[64*STR];
  __shared__ float scv[64];
  short* sU=(short*)uf;
  float* sF=(float*)uf;
  int tid=threadIdx.x, blk=blockIdx.x;
  int b=blk>>10, n=blk&1023;
  int base=((n>>5)<<11) + ((n&31)<<3);
  size_t plane=((size_t)b*64)<<16;
  const float* mT = (mbin[blk]>0.5f)? m1T : m0T;
  const unsigned short* xw=xwb+(size_t)blk*4096;
  const unsigned short* vw2=vw+(size_t)blk*4096;
  int lane=tid&63, wid=tid>>6;
  int pb=wid*16, lr=lane&15, lg=lane>>4;
  // A-frag loads first (longest latency)
  short8v ta[2];
  #pragma unroll
  for(int ks=0;ks<2;ks++) ta[ks]=*(const short8v*)(xw + (pb+lr)*64 + ks*32 + lg*8);
  // ---- P1a: c_j = cvec . t_j + cconst ----
  {
    int tok=tid>>2, part=tid&3;
    float s=0.f;
    #pragma unroll
    for(int i=0;i<16;i++){
      int c=part*16+i;
      s+=us2f(xw[tok*64+c])*cvec[c];
    }
    s+=__shfl_xor(s,1); s+=__shfl_xor(s,2);
    if(part==0) scv[tok]=s+cconst[0];
  }
  // ---- P1b: stage masked V; compute vs = v*sa*(1-mk), packed bf16 (8 VGPR) ----
  unsigned vsp[8];
  #pragma unroll
  for(int k2=0;k2<2;k2++){
    int task=tid+k2*256;
    int c=task>>3, tok0=(task&7)*8;
    uint4 uv=*(const uint4*)(vw2 + c*64 + tok0);
    float4 ma=*(const float4*)(mT + c*64 + tok0);
    float4 mb=*(const float4*)(mT + c*64 + tok0 + 4);
    uint4 sa4=*(const uint4*)(sa_w + ((size_t)blk<<6) + tok0);
    float v0=us2f(uv.x&0xffff), v1=us2f(uv.x>>16);
    float v2=us2f(uv.y&0xffff), v3=us2f(uv.y>>16);
    float v4=us2f(uv.z&0xffff), v5=us2f(uv.z>>16);
    float v6=us2f(uv.w&0xffff), v7=us2f(uv.w>>16);
    uint4 o;
    o.x=pack2(v0*ma.x, v1*ma.y);
    o.y=pack2(v2*ma.z, v3*ma.w);
    o.z=pack2(v4*mb.x, v5*mb.y);
    o.w=pack2(v6*mb.z, v7*mb.w);
    *(uint4*)&sV1[c*STR+tok0]=o;
    vsp[k2*4+0]=pack2(v0*us2f(sa4.x&0xffff)*(1.f-ma.x), v1*us2f(sa4.x>>16)*(1.f-ma.y));
    vsp[k2*4+1]=pack2(v2*us2f(sa4.y&0xffff)*(1.f-ma.z), v3*us2f(sa4.y>>16)*(1.f-ma.w));
    vsp[k2*4+2]=pack2(v4*us2f(sa4.z&0xffff)*(1.f-mb.x), v5*us2f(sa4.z>>16)*(1.f-mb.y));
    vsp[k2*4+3]=pack2(v6*us2f(sa4.w&0xffff)*(1.f-mb.z), v7*us2f(sa4.w>>16)*(1.f-mb.w));
  }
  // ---- P2: u = M^T t (8 MFMAs), u rows -> sU ----
  __builtin_amdgcn_s_setprio(1);
  #pragma unroll
  for(int nt=0;nt<4;nt++){
    f32x4 ua={0.f,0.f,0.f,0.f};
    #pragma unroll
    for(int ks=0;ks<2;ks++){
      short8v afrag=*(const short8v*)(MtB + (nt*16+lr)*64 + ks*32 + lg*8);
      ua=__builtin_amdgcn_mfma_f32_16x16x32_bf16(afrag,ta[ks],ua,0,0,0);
    }
    uint2 w; w.x=pack2(ua[0],ua[1]); w.y=pack2(ua[2],ua[3]);
    *(uint2*)&sU[(pb+lr)*STR + nt*16+lg*4]=w;
  }
  __builtin_amdgcn_s_setprio(0);
  __syncthreads();   // covers sV1, scv (cross-wave); sU is own-wave
  // ---- P3: S = u t^T + c_j ; softmax in place; probs -> sU rows (own-wave) ----
  short8v qa2[2];
  #pragma unroll
  for(int ks=0;ks<2;ks++) qa2[ks]=*(const short8v*)&sU[(pb+lr)*STR + ks*32 + lg*8];
  f32x4 sacc[4];
  __builtin_amdgcn_s_setprio(1);
  #pragma unroll
  for(int nt=0;nt<4;nt++){
    f32x4 a={0.f,0.f,0.f,0.f};
    #pragma unroll
    for(int ks=0;ks<2;ks++){
      short8v kb=*(const short8v*)(xw + (nt*16+lr)*64 + ks*32 + lg*8);
      a=__builtin_amdgcn_mfma_f32_16x16x32_bf16(qa2[ks],kb,a,0,0,0);
    }
    float cj=scv[nt*16+lr];
    #pragma unroll
    for(int r=0;r<4;r++) a[r]+=cj;
    sacc[nt]=a;
  }
  __builtin_amdgcn_s_setprio(0);
  #pragma unroll
  for(int r=0;r<4;r++){
    float mx=fmaxf(fmaxf(sacc[0][r],sacc[1][r]),fmaxf(sacc[2][r],sacc[3][r]));
    #pragma unroll
    for(int m=1;m<16;m<<=1) mx=fmaxf(mx,__shfl_xor(mx,m));
    float e0=__expf(sacc[0][r]-mx), e1=__expf(sacc[1][r]-mx);
    float e2=__expf(sacc[2][r]-mx), e3=__expf(sacc[3][r]-mx);
    float sum=e0+e1+e2+e3;
    #pragma unroll
    for(int m=1;m<16;m<<=1) sum+=__shfl_xor(sum,m);
    float inv=1.f/sum;
    sacc[0][r]=e0*inv; sacc[1][r]=e1*inv; sacc[2][r]=e2*inv; sacc[3][r]=e3*inv;
  }
  #pragma unroll
  for(int nt=0;nt<4;nt++){
    #pragma unroll
    for(int r=0;r<4;r++)
      sU[(pb+lg*4+r)*STR + nt*16+lr]=f2bs(sacc[nt][r]);
  }
  short8v aa[2];
  #pragma unroll
  for(int ks=0;ks<2;ks++) aa[ks]=*(const short8v*)&sU[(pb+lr)*STR + ks*32 + lg*8];
  __syncthreads();   // all probs loaded before sF (aliasing sU) is written
  __builtin_amdgcn_s_setprio(1);
  #pragma unroll
  for(int nt=0;nt<4;nt++){
    f32x4 f={0.f,0.f,0.f,0.f};
    #pragma unroll
    for(int ks=0;ks<2;ks++){
      short8v vb=*(const short8v*)&sV1[(nt*16+lr)*STR + ks*32 + lg*8];
      f=__builtin_amdgcn_mfma_f32_16x16x32_bf16(aa[ks],vb,f,0,0,0);
    }
    #pragma unroll
    for(int r=0;r<4;r++) sF[(pb+lg*4+r)*STRF + nt*16+lr]=f[r];
  }
  __builtin_amdgcn_s_setprio(0);
  __syncthreads();
  // ---- P5: epilogue from packed registers; 16B-contiguous window-row stores ----
  #pragma unroll
  for(int k2=0;k2<2;k2++){
    int task=tid+k2*256;
    int c=task>>3, tok0=(task&7)*8;
    unsigned short ov[8];
    #pragma unroll
    for(int j=0;j<8;j++){
      unsigned w=vsp[k2*4+(j>>1)];
      float vsj=us2f((unsigned short)((j&1)? (w>>16) : (w&0xffff)));
      float f=sF[(tok0+j)*STRF+c];
      ov[j]=(unsigned short)f2bs(f+vsj);
    }
    uint4 o;
    o.x=((unsigned)ov[1]<<16)|ov[0]; o.y=((unsigned)ov[3]<<16)|ov[2];
    o.z=((unsigned)ov[5]<<16)|ov[4]; o.w=((unsigned)ov[7]<<16)|ov[6];
    int pix=base+((tok0>>3)<<8);
    *(uint4*)(img+plane+(((size_t)c)<<16)+pix)=o;
  }
}

// ---------------- K_DWF v2: fused dw dil1+dil2+gelu*ca+img, 4-col groups, vector LDS ----------------
#define DWI 264
__global__ __launch_bounds__(256) void k_dwfuse(const unsigned short* __restrict__ img,
    const float* __restrict__ dw1w, const float* __restrict__ dwb1,
    const float* __restrict__ dw2w, const float* __restrict__ dwb2,
    const float* __restrict__ ca, unsigned short* __restrict__ outb){
  __shared__ float sImg[22*DWI];
  __shared__ float sTmp[20*DWI];
  __shared__ float k1[9], k2[9];
  __shared__ float bb1, bb2, cav;
  int bid=blockIdx.x; int b=bid>>10, c=(bid>>4)&63, sy=bid&15;
  int y0=sy*16;
  int tid=threadIdx.x;
  if(tid<9){ k1[tid]=dw1w[c*9+tid]; k2[tid]=dw2w[c*9+tid]; }
  if(tid==9)  bb1=dwb1[c];
  if(tid==10) bb2=dwb2[c];
  if(tid==11) cav=ca[b*64+c];
  const unsigned short* ip=img+(((size_t)(b*64+c))<<16);
  for(int task=tid;task<1452;task+=256){
    int r=task/66, j=task-r*66;
    int gy=y0-3+r, gx0=4*j-4;
    float4 v=make_float4(0.f,0.f,0.f,0.f);
    if((unsigned)gy<256u && j>=1 && j<=64){
      uint2 u=*(const uint2*)(ip+(gy<<8)+gx0);
      v.x=us2f(u.x&0xffff); v.y=us2f(u.x>>16); v.z=us2f(u.y&0xffff); v.w=us2f(u.y>>16);
    }
    *(float4*)&sImg[r*DWI+4*j]=v;
  }
  __syncthreads();
  for(int task=tid;task<1300;task+=256){
    int r=task/65, g=task-r*65;
    int ty=y0-2+r, tc0=4*g-2;
    float t[4]={bb1,bb1,bb1,bb1};
    #pragma unroll
    for(int dy=0;dy<3;dy++){
      float4 A0=*(const float4*)&sImg[(r+dy)*DWI+4*g];
      float4 A1=*(const float4*)&sImg[(r+dy)*DWI+4*g+4];
      float F[8]={A0.x,A0.y,A0.z,A0.w,A1.x,A1.y,A1.z,A1.w};
      #pragma unroll
      for(int dx=0;dx<3;dx++){
        float kk=k1[dy*3+dx];
        #pragma unroll
        for(int e=0;e<4;e++) t[e]+=F[1+e+dx]*kk;
      }
    }
    float4 res;
    bool rowok=((unsigned)ty<256u);
    #pragma unroll
    for(int e=0;e<4;e++){
      int tc=tc0+e;
      ((float*)&res)[e]= (rowok && (unsigned)tc<256u)? t[e] : 0.f;
    }
    *(float4*)&sTmp[r*DWI+4*g]=res;
  }
  __syncthreads();
  int q=tid&63, rr=tid>>6;
  unsigned short* op=outb+(((size_t)(b*64+c))<<16);
  #pragma unroll
  for(int l4=0;l4<4;l4++){
    int ly=rr*4+l4;
    float cs[4]={bb2,bb2,bb2,bb2};
    #pragma unroll
    for(int dy=0;dy<3;dy++){
      int r=ly+2*dy;
      float4 T0=*(const float4*)&sTmp[r*DWI+4*q];
      float4 T1=*(const float4*)&sTmp[r*DWI+4*q+4];
      float T[8]={T0.x,T0.y,T0.z,T0.w,T1.x,T1.y,T1.z,T1.w};
      #pragma unroll
      for(int dx=0;dx<3;dx++){
        float kk=k2[dy*3+dx];
        #pragma unroll
        for(int e=0;e<4;e++) cs[e]+=T[e+2*dx]*kk;
      }
    }
    float4 C=*(const float4*)&sImg[(ly+3)*DWI+4*q+4];
    float o0=geluf(cs[0])*cav+C.x;
    float o1=geluf(cs[1])*cav+C.y;
    float o2=geluf(cs[2])*cav+C.z;
    float o3=geluf(cs[3])*cav+C.w;
    uint2 u; u.x=pack2(o0,o1); u.y=pack2(o2,o3);
    *(uint2*)(op+((y0+ly)<<8)+4*q)=u;
  }
}

// ---------------- K_FDW v2: ffn depthwise (E bf16) + gelu gate, 4-col groups ----------------
#define FEI 264
__global__ __launch_bounds__(256) void k_ffn_dw_t(const unsigned short* __restrict__ E,
    const float* __restrict__ dwf, unsigned short* __restrict__ g){
  __shared__ unsigned short sE1[18*FEI];
  __shared__ unsigned short sE2[18*FEI];
  __shared__ float k1[9], k2[9];
  int bid=blockIdx.x; int b=bid>>10, c=(bid>>4)&63, sy=bid&15;
  int y0=sy*16;
  int tid=threadIdx.x;
  if(tid<9){ k1[tid]=dwf[c*9+tid]; k2[tid]=dwf[(64+c)*9+tid]; }
  const unsigned short* p1=E+(((size_t)(b*128+c))<<16);
  const unsigned short* p2=E+(((size_t)(b*128+64+c))<<16);
  for(int task=tid;task<1188;task+=256){
    int r=task/66, j=task-r*66;
    int gy=y0-1+r, gx0=4*j-4;
    uint2 u1=make_uint2(0,0), u2=make_uint2(0,0);
    if((unsigned)gy<256u && j>=1 && j<=64){
      u1=*(const uint2*)(p1+(gy<<8)+gx0);
      u2=*(const uint2*)(p2+(gy<<8)+gx0);
    }
    *(uint2*)&sE1[r*FEI+4*j]=u1;
    *(uint2*)&sE2[r*FEI+4*j]=u2;
  }
  __syncthreads();
  int q=tid&63, rr=tid>>6;
  unsigned short* op=g+(((size_t)(b*64+c))<<16);
  #pragma unroll
  for(int l4=0;l4<4;l4++){
    int ly=rr*4+l4;
    float a1[4]={0.f,0.f,0.f,0.f}, a2[4]={0.f,0.f,0.f,0.f};
    #pragma unroll
    for(int dy=0;dy<3;dy++){
      int r=ly+dy;
      unsigned w0=*(const unsigned*)&sE1[r*FEI+4*q+2];
      uint2   w1=*(const uint2*)  &sE1[r*FEI+4*q+4];
      unsigned w2=*(const unsigned*)&sE1[r*FEI+4*q+8];
      float GA[6]={us2f(w0>>16),us2f(w1.x&0xffff),us2f(w1.x>>16),us2f(w1.y&0xffff),us2f(w1.y>>16),us2f(w2&0xffff)};
      unsigned v0=*(const unsigned*)&sE2[r*FEI+4*q+2];
      uint2   v1=*(const uint2*)  &sE2[r*FEI+4*q+4];
      unsigned v2=*(const unsigned*)&sE2[r*FEI+4*q+8];
      float GB[6]={us2f(v0>>16),us2f(v1.x&0xffff),us2f(v1.x>>16),us2f(v1.y&0xffff),us2f(v1.y>>16),us2f(v2&0xffff)};
      #pragma unroll
      for(int dx=0;dx<3;dx++){
        float ka=k1[dy*3+dx], kb=k2[dy*3+dx];
        #pragma unroll
        for(int e=0;e<4;e++){
          a1[e]+=GA[e+dx]*ka;
          a2[e]+=GB[e+dx]*kb;
        }
      }
    }
    float o0=geluf(a1[0])*a2[0];
    float o1=geluf(a1[1])*a2[1];
    float o2=geluf(a1[2])*a2[2];
    float o3=geluf(a1[3])*a2[3];
    uint2 u; u.x=pack2(o0,o1); u.y=pack2(o2,o3);
    *(uint2*)(op+((y0+ly)<<8)+4*q)=u;
  }
}

extern "C" void kernel_launch(void* const* d_in, const int* in_sizes, int n_in,
                              void* d_out, int out_size, void* d_ws, size_t ws_size,
                              hipStream_t stream){
  (void)in_sizes; (void)n_in; (void)out_size; (void)ws_size;
  const void* x  = d_in[0];
  const void* Wm1= d_in[23];
  const void* Wm2= d_in[25];

  char* ws=(char*)d_ws;
  unsigned short* E=(unsigned short*)(ws);
  unsigned short* img=(unsigned short*)(ws+67108864);
  unsigned short* x1b=(unsigned short*)(ws+67108864);
  unsigned short* xwb=(unsigned short*)(ws+134217728);
  unsigned short* outb=(unsigned short*)(ws+134217728);
  unsigned short* gbuf=(unsigned short*)(ws+134217728);
  unsigned short* vw =(unsigned short*)(ws+230686720);
  char* sm = ws+201326592;
  float* x_    =(float*)(sm);              // 16 MB
  unsigned short* sa_w=(unsigned short*)(sm+16777216); // 0.5 MB
  float* xm    =(float*)(sm+17825792);     // 1 MB
  float* var   =(float*)(sm+18874368);     // 16 KB
  float* mbin  =(float*)(sm+18890752);     // 16 KB
  float* h0    =(float*)(sm+18907136);     // 8 KB
  float* h1    =(float*)(sm+18915328);     // 8 KB
  float* m0    =(float*)(sm+18923520);     // 16 KB
  float* m1    =(float*)(sm+18939904);     // 16 KB
  float* capart=(float*)(sm+18956288);     // 64 KB
  float* ca    =(float*)(sm+19021824);     // 1 KB
  int*   flag  =(int*)  (sm+19022848);     // 4 B
  float* wbuf  =(float*)(sm+19023872);     // ~161 KB
  float* m0T   =(float*)(sm+19216384);     // 16 KB
  float* m1T   =(float*)(sm+19232768);     // 16 KB
  short* Wob   =(short*)(sm+19249152);     // 8 KB
  short* Wfib  =(short*)(sm+19257344);     // 16 KB
  short* Wfob  =(short*)(sm+19273728);     // 8 KB
  short* Wvb   =(short*)(sm+19281920);     // 8 KB
  float* WaC   =(float*)(sm+19290112);     // 4 KB
  float* WbC   =(float*)(sm+19294208);     // 4 KB
  float* baC   =(float*)(sm+19298304);     // 64 B
  float* bbC   =(float*)(sm+19298560);     // 64 B
  short* MtB   =(short*)(sm+19298816);     // 8 KB
  float* cvecD =(float*)(sm+19307008);     // 256 B
  float* cconstD=(float*)(sm+19307264);    // 4 B

  static const int din_idx[31]={5,6,7,8,9,10,11,12,13,14,15,16,17,18,19,20,21,22,24,26,27,28,29,30,31,32,33,1,2,3,4};
  static const int szs[31]  ={4096,64,4096,64,4096,64,576,64,576,64,4096,64,1024,16,1024,16,16,16,2048,4096,1024,64,144,1,8192,1152,4096,64,64,64,64};
  CvtArgs ca_args;
  int off=0;
  int offs[31];
  for(int t=0;t<31;t++){
    ca_args.src[t]=d_in[din_idx[t]];
    ca_args.sz[t]=szs[t];
    ca_args.off[t]=off;
    offs[t]=off;
    off+=szs[t];
  }
  const float* Wv  =wbuf+offs[0];  const float* bv  =wbuf+offs[1];
  const float* Wq  =wbuf+offs[2];  const float* bq  =wbuf+offs[3];
  const float* Wk  =wbuf+offs[4];  const float* bk  =wbuf+offs[5];
  const float* dw1 =wbuf+offs[6];  const float* dwb1=wbuf+offs[7];
  const float* dw2 =wbuf+offs[8];  const float* dwb2=wbuf+offs[9];
  const float* Wo  =wbuf+offs[10]; const float* bo  =wbuf+offs[11];
  const float* W_in=wbuf+offs[12]; const float* b_in=wbuf+offs[13];
  const float* Wc  =wbuf+offs[14]; const float* bc  =wbuf+offs[15];
  const float* lnw =wbuf+offs[16]; const float* lnb =wbuf+offs[17];
  const float* bm1 =wbuf+offs[18]; const float* bm2 =wbuf+offs[19];
  const float* Wca =wbuf+offs[20]; const float* bca =wbuf+offs[21];
  const float* Wsa =wbuf+offs[22]; const float* bsa =wbuf+offs[23];
  const float* Wfi =wbuf+offs[24]; const float* dwf =wbuf+offs[25];
  const float* Wfo =wbuf+offs[26];
  const float* wn1 =wbuf+offs[27]; const float* bn1 =wbuf+offs[28];
  const float* wn2 =wbuf+offs[29]; const float* bn2 =wbuf+offs[30];

  hipLaunchKernelGGL(k_cvt,      dim3(31),     dim3(256), 0, stream, ca_args, x, flag, wbuf);
  hipLaunchKernelGGL(k_prep,     dim3(49),     dim3(256), 0, stream, Wo, Wfi, Wfo, Wv, Wq, Wk, bq, bk,
                     W_in, b_in, Wc, bc, bv, Wob, Wfib, Wfob, Wvb, MtB, cvecD, cconstD, WaC, baC, WbC, bbC);
  hipLaunchKernelGGL(k_route,    dim3(512),    dim3(256), 0, stream, x, flag, WaC, baC, WbC, bbC, lnw, lnb, x_, xm, capart);
  hipLaunchKernelGGL(k_sa,       dim3(1024),   dim3(256), 0, stream, x_, Wsa, bsa, sa_w);
  hipLaunchKernelGGL(k_varhvec,  dim3(1536),   dim3(256), 0, stream, xm, var, Wm1, bm1, h0, h1, flag);
  hipLaunchKernelGGL(k_rankmaskca,dim3(1044),  dim3(256), 0, stream, var, mbin, Wm2, bm2, h0, h1,
                     m0, m1, m0T, m1T, capart, Wca, bca, ca, flag);
  hipLaunchKernelGGL(k_convv_mf, dim3(4096),   dim3(256), 0, stream, x, flag, Wvb, bv, mbin, m0T, m1T, vw, xwb);
  hipLaunchKernelGGL(k_attn_mfma,dim3(4096),   dim3(256), 0, stream, xwb, vw, sa_w, mbin, m0T, m1T, MtB, cvecD, cconstD, img);
  hipLaunchKernelGGL(k_dwfuse,   dim3(4096),   dim3(256), 0, stream, img, dw1, dwb1, dw2, dwb2, ca, outb);
  hipLaunchKernelGGL(k_gemm_lnfi,dim3(4096),   dim3(256), 0, stream, outb, Wob, bo, x, wn1, bn1, x1b, Wfib, E, flag);
  hipLaunchKernelGGL(k_ffn_dw_t, dim3(4096),   dim3(256), 0, stream, E, dwf, gbuf);
  hipLaunchKernelGGL(k_gemm_ln,  dim3(4096),   dim3(256), 0, stream, gbuf, Wfob, wbuf, 0, (const void*)x1b, wn2, bn2, d_out, flag, 2, 0);
}

// Round 28
// 443.426 us; speedup vs baseline: 1.0212x; 1.0212x over previous
//
#include <hip/hip_runtime.h>
#include <hip/hip_bf16.h>

typedef __hip_bfloat16 bf16;
typedef __attribute__((ext_vector_type(8))) short short8v;
typedef __attribute__((ext_vector_type(4))) float f32x4;

#define DEV static __device__ __forceinline__

DEV float b2f(bf16 h){ return __bfloat162float(h); }
DEV float us2f(unsigned short u){ unsigned v=((unsigned)u)<<16; float f; __builtin_memcpy(&f,&v,4); return f; }
DEV short f2bs(float f){ bf16 h=__float2bfloat16(f); short s; __builtin_memcpy(&s,&h,2); return s; }
DEV unsigned pack2(float a, float b){ return ((unsigned)(unsigned short)f2bs(b)<<16)|(unsigned short)f2bs(a); }
DEV float lrelu(float x){ return x >= 0.f ? x : 0.1f*x; }
DEV float geluf(float x){ return 0.5f*x*(1.f + erff(x*0.70710678118654752440f)); }
DEV float sigmoidf(float x){ return 1.f/(1.f + expf(-x)); }

// B=4, C=64, H=W=256, HW=65536, WS=8, N=1024 windows/batch, embed=4096

// ---------------- K0b v2: convert small weights to f32 wbuf; self-detect dtype; block0 writes flag ----------------
struct CvtArgs { const void* src[31]; int sz[31]; int off[31]; };
__global__ __launch_bounds__(256) void k_cvt(CvtArgs a, const void* x, int* flag, float* wbuf){
  __shared__ int cnt;
  if(threadIdx.x==0) cnt=0;
  __syncthreads();
  const unsigned short* up=(const unsigned short*)x;
  int c=0;
  for(int k=0;k<16;k++){
    unsigned short u=up[(threadIdx.x*16+k)*2];
    if(((u>>7)&0xFF)==0xFF) c++;
  }
  atomicAdd(&cnt,c);
  __syncthreads();
  int isf32 = (cnt>0);
  if(blockIdx.x==0 && threadIdx.x==0) flag[0]=isf32;
  int t=blockIdx.x; int n=a.sz[t]; const void* s=a.src[t]; float* d=wbuf+a.off[t];
  if(isf32){
    const float* sp=(const float*)s;
    for(int i=threadIdx.x;i<n;i+=256) d[i]=sp[i];
  } else {
    const bf16* sp=(const bf16*)s;
    for(int i=threadIdx.x;i<n;i+=256) d[i]=b2f(sp[i]);
  }
}

// ---------------- K_PREP: merged w2b6 (blocks 0-31) + qkcomp (32-47) + wcomp (48) ----------------
__global__ __launch_bounds__(256) void k_prep(
    const float* __restrict__ wo, const float* __restrict__ wfi,
    const float* __restrict__ wfo, const float* __restrict__ wv,
    const float* __restrict__ wq, const float* __restrict__ wk,
    const float* __restrict__ bq, const float* __restrict__ bk,
    const float* __restrict__ W_in, const float* __restrict__ b_in,
    const float* __restrict__ Wc, const float* __restrict__ bc,
    const float* __restrict__ bv,
    short* __restrict__ Wob, short* __restrict__ Wfib, short* __restrict__ Wfob,
    short* __restrict__ Wvb, short* __restrict__ MtB,
    float* __restrict__ cvec, float* __restrict__ cconst,
    float* __restrict__ Wa, float* __restrict__ ba,
    float* __restrict__ Wb2, float* __restrict__ bb2){
  int bid=blockIdx.x, tid=threadIdx.x;
  if(bid<32){
    int i=bid*256+tid;
    if(i<4096){ Wob[i]=f2bs(wo[i]); Wfob[i]=f2bs(wfo[i]); Wvb[i]=f2bs(wv[i]); }
    if(i<8192) Wfib[i]=f2bs(wfi[i]);
  } else if(bid<48){
    int idx=(bid-32)*256+tid;
    if(idx<4096){
      int cp=idx>>6, c=idx&63;
      float s=0.f;
      for(int o=0;o<64;o++) s+=wq[o*64+c]*wk[o*64+cp];
      MtB[cp*64+c]=f2bs(s);
    }
    if(bid==32){
      if(tid<64){
        float s=0.f;
        for(int o=0;o<64;o++) s+=bq[o]*wk[o*64+tid];
        cvec[tid]=s;
      } else if(tid==64){
        float s=0.f;
        for(int o=0;o<64;o++) s+=bq[o]*bk[o];
        cconst[0]=s;
      }
    }
  } else {
    #pragma unroll
    for(int ii=0;ii<4;ii++){
      int idx=tid+ii*256;
      int i=idx>>6, c=idx&63;
      float sa=0.f, sb=0.f;
      for(int k=0;k<64;k++){
        float wv2=wv[k*64+c];
        sa+=W_in[i*64+k]*wv2;
        sb+=Wc[i*64+k]*wv2;
      }
      Wa[idx]=sa; Wb2[idx]=sb;
    }
    if(tid<16){
      float sa=0.f, sb=0.f;
      for(int k=0;k<64;k++){ sa+=W_in[tid*64+k]*bv[k]; sb+=Wc[tid*64+k]*bv[k]; }
      ba[tid]=sa+b_in[tid]; bb2[tid]=sb+bc[tid];
    }
  }
}

// ---------------- K1 v2: conv_v MFMA -> vw, PLUS masked token-major xwb ----------------
__global__ __launch_bounds__(256) void k_convv_mf(
    const void* __restrict__ in, const int* __restrict__ fl,
    const short* __restrict__ Wvb, const float* __restrict__ bv,
    const float* __restrict__ mbin, const float* __restrict__ m0T, const float* __restrict__ m1T,
    unsigned short* __restrict__ vw, unsigned short* __restrict__ xwb){
  __shared__ float Xf[64*66];
  int tid=threadIdx.x;
  int g0=blockIdx.x*64; int b=g0>>16, p0=g0&65535;
  int c=tid>>2, q=tid&3;
  size_t base=(((size_t)(b*64+c))<<16) + p0;
  if(fl[0]){
    const float* ip=(const float*)in + base;
    #pragma unroll
    for(int j=0;j<4;j++){
      int po=q*16+j*4;
      float4 xv=*(const float4*)(ip+po);
      *(float2*)&Xf[c*66+po]=make_float2(xv.x,xv.y);
      *(float2*)&Xf[c*66+po+2]=make_float2(xv.z,xv.w);
    }
  } else {
    const unsigned short* ip=(const unsigned short*)in + base;
    #pragma unroll
    for(int j=0;j<4;j++){
      int po=q*16+j*4;
      uint2 u=*(const uint2*)(ip+po);
      *(float2*)&Xf[c*66+po]=make_float2(us2f(u.x&0xffff),us2f(u.x>>16));
      *(float2*)&Xf[c*66+po+2]=make_float2(us2f(u.y&0xffff),us2f(u.y>>16));
    }
  }
  __syncthreads();
  int lane=tid&63, wid=tid>>6;
  int lr=lane&15, lg=lane>>4;
  int pix0=wid*16;
  short8v bfrag[2];
  #pragma unroll
  for(int ks=0;ks<2;ks++){
    short8v v;
    #pragma unroll
    for(int i=0;i<8;i++) v[i]=f2bs(Xf[(ks*32+lg*8+i)*66 + pix0+lr]);
    bfrag[ks]=v;
  }
  int y=p0>>8;
  int xx=(p0&255)+pix0+lr;
  int n=((y>>3)<<5)|(xx>>3), tok=((y&7)<<3)|(xx&7);
  unsigned short* wp=vw + (((size_t)(b*1024+n))<<12) + tok;
  #pragma unroll
  for(int nt=0;nt<4;nt++){
    f32x4 acc;
    #pragma unroll
    for(int r=0;r<4;r++) acc[r]=bv[nt*16+lg*4+r];
    #pragma unroll
    for(int ks=0;ks<2;ks++){
      short8v afrag=*(const short8v*)(Wvb + (nt*16+lr)*64 + ks*32 + lg*8);
      acc=__builtin_amdgcn_mfma_f32_16x16x32_bf16(afrag,bfrag[ks],acc,0,0,0);
    }
    #pragma unroll
    for(int r=0;r<4;r++){
      int m=nt*16+lg*4+r;
      wp[(size_t)m*64]=(unsigned short)f2bs(acc[r]);
    }
  }
  int nw0=((y>>3)<<5) | ((p0&255)>>3);
  int trow=(y&7)*8;
  #pragma unroll
  for(int k2=0;k2<2;k2++){
    int task=tid+k2*256;
    int w=task>>6, rem=task&63, j=rem>>3, cg=rem&7;
    int nn=nw0+w;
    const float* mT=(mbin[b*1024+nn]>0.5f)? m1T : m0T;
    int tk=trow+j;
    int pixl=w*8+j;
    unsigned short ov[8];
    #pragma unroll
    for(int i=0;i<8;i++){
      int ch=cg*8+i;
      ov[i]=(unsigned short)f2bs(Xf[ch*66+pixl]*mT[ch*64+tk]);
    }
    uint4 o;
    o.x=((unsigned)ov[1]<<16)|ov[0]; o.y=((unsigned)ov[3]<<16)|ov[2];
    o.z=((unsigned)ov[5]<<16)|ov[4]; o.w=((unsigned)ov[7]<<16)|ov[6];
    *(uint4*)(xwb + (((size_t)(b*1024+nn))<<12) + tk*64 + cg*8)=o;
  }
}

// ---------------- K_GLF: fused Wo-GEMM + residual + LN -> x1b, then ffn_in GEMM -> E ----------------
__global__ __launch_bounds__(256) void k_gemm_lnfi(
    const unsigned short* __restrict__ in,
    const short* __restrict__ Wb, const float* __restrict__ bias,
    const void* __restrict__ basex,
    const float* __restrict__ lnw, const float* __restrict__ lnb,
    unsigned short* __restrict__ xout,
    const short* __restrict__ Wfib,
    unsigned short* __restrict__ E,
    const int* __restrict__ fl){
  __shared__ short Ain[64*72];
  int tid=threadIdx.x;
  int g0=blockIdx.x*64; int b=g0>>16, p0=g0&65535;
  int c=tid>>2, q=tid&3;
  {
    const unsigned short* ip=in + (((size_t)(b*64+c))<<16) + p0;
    #pragma unroll
    for(int j=0;j<4;j++){
      int po=q*16+j*4;
      uint2 u=*(const uint2*)(ip+po);
      Ain[(po+0)*72+c]=(short)(u.x&0xffff); Ain[(po+1)*72+c]=(short)(u.x>>16);
      Ain[(po+2)*72+c]=(short)(u.y&0xffff); Ain[(po+3)*72+c]=(short)(u.y>>16);
    }
  }
  __syncthreads();
  int lane=tid&63, wid=tid>>6;
  int lr=lane&15, lg=lane>>4;
  int pix0=wid*16;
  short8v bfrag[2];
  #pragma unroll
  for(int ks=0;ks<2;ks++) bfrag[ks]=*(const short8v*)&Ain[(pix0+lr)*72 + ks*32 + lg*8];
  __syncthreads();   // all waves done reading Ain before it is overwritten below
  float rl[16];
  #pragma unroll
  for(int nt=0;nt<4;nt++){
    f32x4 acc;
    #pragma unroll
    for(int r=0;r<4;r++) acc[r]=bias[nt*16+lg*4+r];
    #pragma unroll
    for(int ks=0;ks<2;ks++){
      short8v afrag=*(const short8v*)(Wb + (nt*16+lr)*64 + ks*32 + lg*8);
      acc=__builtin_amdgcn_mfma_f32_16x16x32_bf16(afrag,bfrag[ks],acc,0,0,0);
    }
    #pragma unroll
    for(int r=0;r<4;r++) rl[nt*4+r]=acc[r];
  }
  int pix=p0+pix0+lr;
  if(fl[0]){
    const float* xp=(const float*)basex;
    #pragma unroll
    for(int nt=0;nt<4;nt++)
      #pragma unroll
      for(int r=0;r<4;r++)
        rl[nt*4+r]+=xp[(((size_t)(b*64+nt*16+lg*4+r))<<16)+pix];
  } else {
    const unsigned short* xp=(const unsigned short*)basex;
    #pragma unroll
    for(int nt=0;nt<4;nt++)
      #pragma unroll
      for(int r=0;r<4;r++)
        rl[nt*4+r]+=us2f(xp[(((size_t)(b*64+nt*16+lg*4+r))<<16)+pix]);
  }
  float s=0.f;
  #pragma unroll
  for(int i=0;i<16;i++) s+=rl[i];
  s+=__shfl_xor(s,16); s+=__shfl_xor(s,32);
  float mean=s*(1.f/64.f);
  float qv=0.f;
  #pragma unroll
  for(int i=0;i<16;i++){ float d=rl[i]-mean; qv+=d*d; }
  qv+=__shfl_xor(qv,16); qv+=__shfl_xor(qv,32);
  float inv=1.f/sqrtf(qv*(1.f/64.f)+1e-6f);
  // write x1b (bf16) and the same bits into the LDS tile (token-major rows)
  #pragma unroll
  for(int nt=0;nt<4;nt++){
    unsigned short sb[4];
    #pragma unroll
    for(int r=0;r<4;r++){
      int m=nt*16+lg*4+r;
      unsigned short v=(unsigned short)f2bs(lnw[m]*((rl[nt*4+r]-mean)*inv)+lnb[m]);
      sb[r]=v;
      xout[(((size_t)(b*64+m))<<16)+pix]=v;
    }
    uint2 w;
    w.x=((unsigned)sb[1]<<16)|sb[0];
    w.y=((unsigned)sb[3]<<16)|sb[2];
    *(uint2*)&Ain[(pix0+lr)*72 + nt*16+lg*4]=w;
  }
  __syncthreads();
  // ffn_in GEMM: 128 output channels from LN'd tile
  short8v bfrag2[2];
  #pragma unroll
  for(int ks=0;ks<2;ks++) bfrag2[ks]=*(const short8v*)&Ain[(pix0+lr)*72 + ks*32 + lg*8];
  #pragma unroll
  for(int nt=0;nt<8;nt++){
    f32x4 acc={0.f,0.f,0.f,0.f};
    #pragma unroll
    for(int ks=0;ks<2;ks++){
      short8v afrag=*(const short8v*)(Wfib + (nt*16+lr)*64 + ks*32 + lg*8);
      acc=__builtin_amdgcn_mfma_f32_16x16x32_bf16(afrag,bfrag2[ks],acc,0,0,0);
    }
    #pragma unroll
    for(int r=0;r<4;r++){
      int m=nt*16+lg*4+r;
      E[(((size_t)(b*128+m))<<16) + pix]=(unsigned short)f2bs(acc[r]);
    }
  }
}

// ---------------- K_GL: MFMA GEMM (64 och) + residual-add + LayerNorm fused ----------------
__global__ __launch_bounds__(256) void k_gemm_ln(
    const unsigned short* __restrict__ in,
    const short* __restrict__ Wb, const float* __restrict__ bias, int has_bias,
    const void* __restrict__ basex,
    const float* __restrict__ lnw, const float* __restrict__ lnb,
    void* __restrict__ out,
    const int* __restrict__ fl, int base_mode, int out_mode){
  __shared__ short Ain[64*72];
  int tid=threadIdx.x;
  int g0=blockIdx.x*64; int b=g0>>16, p0=g0&65535;
  int c=tid>>2, q=tid&3;
  {
    const unsigned short* ip=in + (((size_t)(b*64+c))<<16) + p0;
    #pragma unroll
    for(int j=0;j<4;j++){
      int po=q*16+j*4;
      uint2 u=*(const uint2*)(ip+po);
      Ain[(po+0)*72+c]=(short)(u.x&0xffff); Ain[(po+1)*72+c]=(short)(u.x>>16);
      Ain[(po+2)*72+c]=(short)(u.y&0xffff); Ain[(po+3)*72+c]=(short)(u.y>>16);
    }
  }
  __syncthreads();
  int lane=tid&63, wid=tid>>6;
  int lr=lane&15, lg=lane>>4;
  int pix0=wid*16;
  short8v bfrag[2];
  #pragma unroll
  for(int ks=0;ks<2;ks++) bfrag[ks]=*(const short8v*)&Ain[(pix0+lr)*72 + ks*32 + lg*8];
  float rl[16];
  #pragma unroll
  for(int nt=0;nt<4;nt++){
    f32x4 acc;
    if(has_bias){
      #pragma unroll
      for(int r=0;r<4;r++) acc[r]=bias[nt*16+lg*4+r];
    } else {
      acc=(f32x4){0.f,0.f,0.f,0.f};
    }
    #pragma unroll
    for(int ks=0;ks<2;ks++){
      short8v afrag=*(const short8v*)(Wb + (nt*16+lr)*64 + ks*32 + lg*8);
      acc=__builtin_amdgcn_mfma_f32_16x16x32_bf16(afrag,bfrag[ks],acc,0,0,0);
    }
    #pragma unroll
    for(int r=0;r<4;r++) rl[nt*4+r]=acc[r];
  }
  int pix=p0+pix0+lr;
  bool bf32 = (base_mode==1) || (base_mode==0 && fl[0]);
  if(bf32){
    const float* xp=(const float*)basex;
    #pragma unroll
    for(int nt=0;nt<4;nt++)
      #pragma unroll
      for(int r=0;r<4;r++)
        rl[nt*4+r]+=xp[(((size_t)(b*64+nt*16+lg*4+r))<<16)+pix];
  } else {
    const unsigned short* xp=(const unsigned short*)basex;
    #pragma unroll
    for(int nt=0;nt<4;nt++)
      #pragma unroll
      for(int r=0;r<4;r++)
        rl[nt*4+r]+=us2f(xp[(((size_t)(b*64+nt*16+lg*4+r))<<16)+pix]);
  }
  float s=0.f;
  #pragma unroll
  for(int i=0;i<16;i++) s+=rl[i];
  s+=__shfl_xor(s,16); s+=__shfl_xor(s,32);
  float mean=s*(1.f/64.f);
  float qv=0.f;
  #pragma unroll
  for(int i=0;i<16;i++){ float d=rl[i]-mean; qv+=d*d; }
  qv+=__shfl_xor(qv,16); qv+=__shfl_xor(qv,32);
  float inv=1.f/sqrtf(qv*(1.f/64.f)+1e-6f);
  bool of32 = (out_mode==1) || (out_mode==0 && fl[0]);
  if(of32){
    float* op=(float*)out;
    #pragma unroll
    for(int nt=0;nt<4;nt++)
      #pragma unroll
      for(int r=0;r<4;r++){
        int m=nt*16+lg*4+r;
        op[(((size_t)(b*64+m))<<16)+pix]=lnw[m]*((rl[nt*4+r]-mean)*inv)+lnb[m];
      }
  } else {
    unsigned short* op=(unsigned short*)out;
    #pragma unroll
    for(int nt=0;nt<4;nt++)
      #pragma unroll
      for(int r=0;r<4;r++){
        int m=nt*16+lg*4+r;
        op[(((size_t)(b*64+m))<<16)+pix]=(unsigned short)f2bs(lnw[m]*((rl[nt*4+r]-mean)*inv)+lnb[m]);
      }
  }
}

// ---------------- K2: route from x with composed weights (2 pix/thread, f32) ----------------
__global__ __launch_bounds__(256) void k_route(const void* __restrict__ x, const int* __restrict__ fl,
    const float* __restrict__ Wa, const float* __restrict__ ba,
    const float* __restrict__ Wb2, const float* __restrict__ bb2,
    const float* __restrict__ lnw, const float* __restrict__ lnb,
    float* __restrict__ x_, float* __restrict__ xm, float* __restrict__ capart){
  __shared__ float wA[1024], wB[1024], sba[16], sbb[16], slw[16], slb[16];
  __shared__ float sred[4][16];
  int tid=threadIdx.x;
  for(int i=tid;i<1024;i+=256){ wA[i]=Wa[i]; wB[i]=Wb2[i]; }
  if(tid<16){ sba[tid]=ba[tid]; sbb[tid]=bb2[tid]; slw[tid]=lnw[tid]; slb[tid]=lnb[tid]; }
  __syncthreads();
  int g=blockIdx.x*512+tid*2; int b=g>>16, p=g&65535;
  float2 aA[16], aB[16];
  #pragma unroll
  for(int i=0;i<16;i++){ aA[i]=make_float2(sba[i],sba[i]); aB[i]=make_float2(sbb[i],sbb[i]); }
  size_t base=(((size_t)b*64)<<16)+p;
  if(fl[0]){
    const float* vp=(const float*)x+base;
    for(int c=0;c<64;c++){
      float2 vv=*(const float2*)(vp+(((size_t)c)<<16));
      #pragma unroll
      for(int i=0;i<16;i++){
        float wa=wA[(i<<6)+c], wb=wB[(i<<6)+c];
        aA[i].x+=wa*vv.x; aA[i].y+=wa*vv.y;
        aB[i].x+=wb*vv.x; aB[i].y+=wb*vv.y;
      }
    }
  } else {
    const unsigned short* vp=(const unsigned short*)x+base;
    for(int c=0;c<64;c++){
      unsigned u=*(const unsigned*)(vp+(((size_t)c)<<16));
      float v0=us2f(u&0xffff), v1=us2f(u>>16);
      #pragma unroll
      for(int i=0;i<16;i++){
        float wa=wA[(i<<6)+c], wb=wB[(i<<6)+c];
        aA[i].x+=wa*v0; aA[i].y+=wa*v1;
        aB[i].x+=wb*v0; aB[i].y+=wb*v1;
      }
    }
  }
  float s0=0.f,s1=0.f;
  #pragma unroll
  for(int i=0;i<16;i++){ aA[i].x=lrelu(aA[i].x); aA[i].y=lrelu(aA[i].y); s0+=aA[i].x; s1+=aA[i].y; }
  float2 xmst; xmst.x=s0*(1.f/16.f); xmst.y=s1*(1.f/16.f);
  *(float2*)(xm+g)=xmst;
  float u0=0.f,u1=0.f;
  #pragma unroll
  for(int i=0;i<16;i++){ u0+=aB[i].x; u1+=aB[i].y; }
  u0*=(1.f/16.f); u1*=(1.f/16.f);
  float q0=0.f,q1=0.f;
  #pragma unroll
  for(int i=0;i<16;i++){ float d0=aB[i].x-u0, d1=aB[i].y-u1; q0+=d0*d0; q1+=d1*d1; }
  q0*=(1.f/16.f); q1*=(1.f/16.f);
  float i0=1.f/sqrtf(q0+1e-6f), i1=1.f/sqrtf(q1+1e-6f);
  float red[16];
  float* xp=x_+(((size_t)b*16)<<16)+p;
  #pragma unroll
  for(int i=0;i<16;i++){
    float xv0=lrelu(slw[i]*((aB[i].x-u0)*i0)+slb[i]);
    float xv1=lrelu(slw[i]*((aB[i].y-u1)*i1)+slb[i]);
    float2 st; st.x=xv0; st.y=xv1;
    *(float2*)(xp+(((size_t)i)<<16))=st;
    red[i]=xv0+xv1;
  }
  int lane=tid&63, wid=tid>>6;
  #pragma unroll
  for(int i=0;i<16;i++){
    float val=red[i];
    for(int m=32;m>0;m>>=1) val+=__shfl_xor(val,m);
    if(lane==0) sred[wid][i]=val;
  }
  __syncthreads();
  if(tid<16) capart[blockIdx.x*16+tid]=sred[0][tid]+sred[1][tid]+sred[2][tid]+sred[3][tid];
}

// ---------------- K3: sa = sigmoid(conv3x3(x_)) -> window-major bf16 ----------------
__global__ __launch_bounds__(256) void k_sa(const float* __restrict__ x_,
    const float* __restrict__ Wsa, const float* __restrict__ bsa, unsigned short* __restrict__ sa_w){
  __shared__ float w[144]; __shared__ float bb;
  int tid=threadIdx.x;
  if(tid<144) w[tid]=Wsa[tid];
  if(tid==0) bb=bsa[0];
  __syncthreads();
  int pix=blockIdx.x*256+tid; int b=pix>>16, p=pix&65535;
  int y=p>>8, xx=p&255;
  float acc=bb;
  #pragma unroll
  for(int i=0;i<16;i++){
    const float* pl=x_+(((size_t)(b*16+i))<<16);
    #pragma unroll
    for(int ky=0;ky<3;ky++){
      int yy=y+ky-1;
      if((unsigned)yy<256u){
        #pragma unroll
        for(int kx=0;kx<3;kx++){
          int x2=xx+kx-1;
          if((unsigned)x2<256u) acc+=pl[(yy<<8)+x2]*w[i*9+ky*3+kx];
        }
      }
    }
  }
  int n=((y>>3)<<5)|(xx>>3), tok=((y&7)<<3)|(xx&7);
  sa_w[(((size_t)(b<<10)+n)<<6)+tok]=(unsigned short)f2bs(sigmoidf(acc));
}

// ---------------- K_VH: merged per-window variance (blocks 0-1023) + Wm1 rowsums (1024-1535) ----------------
__global__ __launch_bounds__(256) void k_varhvec(const float* __restrict__ xm, float* __restrict__ var,
    const void* __restrict__ Wm1, const float* __restrict__ bm1,
    float* __restrict__ h0, float* __restrict__ h1, const int* __restrict__ fl){
  int bid=blockIdx.x, tid=threadIdx.x;
  int w=tid>>6, l=tid&63;
  if(bid<1024){
    int blk=bid*4+w;
    int b=blk>>10, n=blk&1023;
    int pix=((n>>5)<<11) + ((n&31)<<3) + ((l>>3)<<8) + (l&7);
    float val=xm[(b<<16)+pix];
    float s=val;
    for(int m=32;m>0;m>>=1) s+=__shfl_xor(s,m);
    float mean=s*(1.f/64.f);
    float d=val-mean; float q=d*d;
    for(int m=32;m>0;m>>=1) q+=__shfl_xor(q,m);
    if(l==0) var[blk]=q*(1.f/63.f);
  } else {
    int j=(bid-1024)*4+w;
    float s=0.f;
    if(fl[0]){
      const float* row=(const float*)Wm1+((size_t)j<<12);
      for(int k=l;k<4096;k+=64) s+=row[k];
    } else {
      const bf16* row=(const bf16*)Wm1+((size_t)j<<12);
      for(int k=l;k<4096;k+=64) s+=b2f(row[k]);
    }
    for(int m=32;m>0;m>>=1) s+=__shfl_xor(s,m);
    if(l==0){ float bb=bm1[j]; h0[j]=lrelu(bb); h1[j]=lrelu(bb+s); }
  }
}

// ---------------- K_RMC: merged rank (0-15) + mask (16-1039, 4 rows/block) + ca (1040-1043) ----------------
__global__ __launch_bounds__(256) void k_rankmaskca(
    const float* __restrict__ var, float* __restrict__ mbin,
    const void* __restrict__ Wm2, const float* __restrict__ bm2,
    const float* __restrict__ h0, const float* __restrict__ h1,
    float* __restrict__ m0, float* __restrict__ m1,
    float* __restrict__ m0T, float* __restrict__ m1T,
    const float* __restrict__ capart, const float* __restrict__ Wca,
    const float* __restrict__ bca, float* __restrict__ ca,
    const int* __restrict__ fl){
  __shared__ float va[1024];
  __shared__ float cm[16];
  int bid=blockIdx.x, tid=threadIdx.x;
  if(bid<16){
    int b=bid>>2, seg=bid&3;
    for(int i=tid;i<1024;i+=256) va[i]=var[(b<<10)+i];
    __syncthreads();
    int n=seg*256+tid;
    float vn=va[n]; int r=0;
    for(int m=0;m<1024;m++){ float vm=va[m]; r += (vm<vn) || (vm==vn && m<n); }
    mbin[(b<<10)+n] = (r<512)?0.f:1.f;
  } else if(bid<1040){
    int w=tid>>6, l=tid&63;
    int e=(bid-16)*4+w;
    float p0=0.f,p1=0.f;
    if(fl[0]){
      const float* row=(const float*)Wm2+((size_t)e<<11);
      for(int j=l;j<2048;j+=64){ float wv=row[j]; p0+=wv*h0[j]; p1+=wv*h1[j]; }
    } else {
      const bf16* row=(const bf16*)Wm2+((size_t)e<<11);
      for(int j=l;j<2048;j+=64){ float wv=b2f(row[j]); p0+=wv*h0[j]; p1+=wv*h1[j]; }
    }
    for(int m=32;m>0;m>>=1){ p0+=__shfl_xor(p0,m); p1+=__shfl_xor(p1,m); }
    if(l==0){
      float bb=bm2[e]; float v0=p0+bb, v1=p1+bb;
      m0[e]=v0; m1[e]=v1;
      int te=(e&63)*64+(e>>6);
      m0T[te]=v0; m1T[te]=v1;
    }
  } else {
    int b=bid-1040;
    if(tid<16){
      float s=0.f;
      for(int blk=0;blk<128;blk++) s+=capart[((b*128)+blk)*16+tid];
      cm[tid]=s*(1.f/65536.f);
    }
    __syncthreads();
    if(tid<64){
      float a=bca[tid];
      #pragma unroll
      for(int i=0;i<16;i++) a+=Wca[(tid<<4)+i]*cm[i];
      ca[(b<<6)+tid]=sigmoidf(a);
    }
  }
}

// ---------------- K9 v7: attention; in-place softmax (VGPR trim) + setprio around MFMA ----------------
#define STR 72
#define STRF 65
__global__ __launch_bounds__(256) void k_attn_mfma(
    const unsigned short* __restrict__ xwb, const unsigned short* __restrict__ vw,
    const unsigned short* __restrict__ sa_w, const float* __restrict__ mbin,
    const float* __restrict__ m0T, const float* __restrict__ m1T,
    const short* __restrict__ MtB, const float* __restrict__ cvec, const float* __restrict__ cconst,
    unsigned short* __restrict__ img){
  __shared__ __align__(16) char uf[16640];   // sU (bf16 u/probs) U sF (f32 [64][65])
  __shared__ short sV1[64*STR];
  __shared__ float scv[64];
  short* sU=(short*)uf;
  float* sF=(float*)uf;
  int tid=threadIdx.x, blk=blockIdx.x;
  int b=blk>>10, n=blk&1023;
  int base=((n>>5)<<11) + ((n&31)<<3);
  size_t plane=((size_t)b*64)<<16;
  const float* mT = (mbin[blk]>0.5f)? m1T : m0T;
  const unsigned short* xw=xwb+(size_t)blk*4096;
  const unsigned short* vw2=vw+(size_t)blk*4096;
  int lane=tid&63, wid=tid>>6;
  int pb=wid*16, lr=lane&15, lg=lane>>4;
  // A-frag loads first (longest latency)
  short8v ta[2];
  #pragma unroll
  for(int ks=0;ks<2;ks++) ta[ks]=*(const short8v*)(xw + (pb+lr)*64 + ks*32 + lg*8);
  // ---- P1a: c_j = cvec . t_j + cconst ----
  {
    int tok=tid>>2, part=tid&3;
    float s=0.f;
    #pragma unroll
    for(int i=0;i<16;i++){
      int c=part*16+i;
      s+=us2f(xw[tok*64+c])*cvec[c];
    }
    s+=__shfl_xor(s,1); s+=__shfl_xor(s,2);
    if(part==0) scv[tok]=s+cconst[0];
  }
  // ---- P1b: stage masked V; compute vs = v*sa*(1-mk), packed bf16 (8 VGPR) ----
  unsigned vsp[8];
  #pragma unroll
  for(int k2=0;k2<2;k2++){
    int task=tid+k2*256;
    int c=task>>3, tok0=(task&7)*8;
    uint4 uv=*(const uint4*)(vw2 + c*64 + tok0);
    float4 ma=*(const float4*)(mT + c*64 + tok0);
    float4 mb=*(const float4*)(mT + c*64 + tok0 + 4);
    uint4 sa4=*(const uint4*)(sa_w + ((size_t)blk<<6) + tok0);
    float v0=us2f(uv.x&0xffff), v1=us2f(uv.x>>16);
    float v2=us2f(uv.y&0xffff), v3=us2f(uv.y>>16);
    float v4=us2f(uv.z&0xffff), v5=us2f(uv.z>>16);
    float v6=us2f(uv.w&0xffff), v7=us2f(uv.w>>16);
    uint4 o;
    o.x=pack2(v0*ma.x, v1*ma.y);
    o.y=pack2(v2*ma.z, v3*ma.w);
    o.z=pack2(v4*mb.x, v5*mb.y);
    o.w=pack2(v6*mb.z, v7*mb.w);
    *(uint4*)&sV1[c*STR+tok0]=o;
    vsp[k2*4+0]=pack2(v0*us2f(sa4.x&0xffff)*(1.f-ma.x), v1*us2f(sa4.x>>16)*(1.f-ma.y));
    vsp[k2*4+1]=pack2(v2*us2f(sa4.y&0xffff)*(1.f-ma.z), v3*us2f(sa4.y>>16)*(1.f-ma.w));
    vsp[k2*4+2]=pack2(v4*us2f(sa4.z&0xffff)*(1.f-mb.x), v5*us2f(sa4.z>>16)*(1.f-mb.y));
    vsp[k2*4+3]=pack2(v6*us2f(sa4.w&0xffff)*(1.f-mb.z), v7*us2f(sa4.w>>16)*(1.f-mb.w));
  }
  // ---- P2: u = M^T t (8 MFMAs), u rows -> sU ----
  __builtin_amdgcn_s_setprio(1);
  #pragma unroll
  for(int nt=0;nt<4;nt++){
    f32x4 ua={0.f,0.f,0.f,0.f};
    #pragma unroll
    for(int ks=0;ks<2;ks++){
      short8v afrag=*(const short8v*)(MtB + (nt*16+lr)*64 + ks*32 + lg*8);
      ua=__builtin_amdgcn_mfma_f32_16x16x32_bf16(afrag,ta[ks],ua,0,0,0);
    }
    uint2 w; w.x=pack2(ua[0],ua[1]); w.y=pack2(ua[2],ua[3]);
    *(uint2*)&sU[(pb+lr)*STR + nt*16+lg*4]=w;
  }
  __builtin_amdgcn_s_setprio(0);
  __syncthreads();   // covers sV1, scv (cross-wave); sU is own-wave
  // ---- P3: S = u t^T + c_j ; softmax in place; probs -> sU rows (own-wave) ----
  short8v qa2[2];
  #pragma unroll
  for(int ks=0;ks<2;ks++) qa2[ks]=*(const short8v*)&sU[(pb+lr)*STR + ks*32 + lg*8];
  f32x4 sacc[4];
  __builtin_amdgcn_s_setprio(1);
  #pragma unroll
  for(int nt=0;nt<4;nt++){
    f32x4 a={0.f,0.f,0.f,0.f};
    #pragma unroll
    for(int ks=0;ks<2;ks++){
      short8v kb=*(const short8v*)(xw + (nt*16+lr)*64 + ks*32 + lg*8);
      a=__builtin_amdgcn_mfma_f32_16x16x32_bf16(qa2[ks],kb,a,0,0,0);
    }
    float cj=scv[nt*16+lr];
    #pragma unroll
    for(int r=0;r<4;r++) a[r]+=cj;
    sacc[nt]=a;
  }
  __builtin_amdgcn_s_setprio(0);
  #pragma unroll
  for(int r=0;r<4;r++){
    float mx=fmaxf(fmaxf(sacc[0][r],sacc[1][r]),fmaxf(sacc[2][r],sacc[3][r]));
    #pragma unroll
    for(int m=1;m<16;m<<=1) mx=fmaxf(mx,__shfl_xor(mx,m));
    float e0=__expf(sacc[0][r]-mx), e1=__expf(sacc[1][r]-mx);
    float e2=__expf(sacc[2][r]-mx), e3=__expf(sacc[3][r]-mx);
    float sum=e0+e1+e2+e3;
    #pragma unroll
    for(int m=1;m<16;m<<=1) sum+=__shfl_xor(sum,m);
    float inv=1.f/sum;
    sacc[0][r]=e0*inv; sacc[1][r]=e1*inv; sacc[2][r]=e2*inv; sacc[3][r]=e3*inv;
  }
  #pragma unroll
  for(int nt=0;nt<4;nt++){
    #pragma unroll
    for(int r=0;r<4;r++)
      sU[(pb+lg*4+r)*STR + nt*16+lr]=f2bs(sacc[nt][r]);
  }
  short8v aa[2];
  #pragma unroll
  for(int ks=0;ks<2;ks++) aa[ks]=*(const short8v*)&sU[(pb+lr)*STR + ks*32 + lg*8];
  __syncthreads();   // all probs loaded before sF (aliasing sU) is written
  __builtin_amdgcn_s_setprio(1);
  #pragma unroll
  for(int nt=0;nt<4;nt++){
    f32x4 f={0.f,0.f,0.f,0.f};
    #pragma unroll
    for(int ks=0;ks<2;ks++){
      short8v vb=*(const short8v*)&sV1[(nt*16+lr)*STR + ks*32 + lg*8];
      f=__builtin_amdgcn_mfma_f32_16x16x32_bf16(aa[ks],vb,f,0,0,0);
    }
    #pragma unroll
    for(int r=0;r<4;r++) sF[(pb+lg*4+r)*STRF + nt*16+lr]=f[r];
  }
  __builtin_amdgcn_s_setprio(0);
  __syncthreads();
  // ---- P5: epilogue from packed registers; 16B-contiguous window-row stores ----
  #pragma unroll
  for(int k2=0;k2<2;k2++){
    int task=tid+k2*256;
    int c=task>>3, tok0=(task&7)*8;
    unsigned short ov[8];
    #pragma unroll
    for(int j=0;j<8;j++){
      unsigned w=vsp[k2*4+(j>>1)];
      float vsj=us2f((unsigned short)((j&1)? (w>>16) : (w&0xffff)));
      float f=sF[(tok0+j)*STRF+c];
      ov[j]=(unsigned short)f2bs(f+vsj);
    }
    uint4 o;
    o.x=((unsigned)ov[1]<<16)|ov[0]; o.y=((unsigned)ov[3]<<16)|ov[2];
    o.z=((unsigned)ov[5]<<16)|ov[4]; o.w=((unsigned)ov[7]<<16)|ov[6];
    int pix=base+((tok0>>3)<<8);
    *(uint4*)(img+plane+(((size_t)c)<<16)+pix)=o;
  }
}

// ---------------- K_DWF v2: fused dw dil1+dil2+gelu*ca+img, 4-col groups, vector LDS ----------------
#define DWI 264
__global__ __launch_bounds__(256) void k_dwfuse(const unsigned short* __restrict__ img,
    const float* __restrict__ dw1w, const float* __restrict__ dwb1,
    const float* __restrict__ dw2w, const float* __restrict__ dwb2,
    const float* __restrict__ ca, unsigned short* __restrict__ outb){
  __shared__ float sImg[22*DWI];
  __shared__ float sTmp[20*DWI];
  __shared__ float k1[9], k2[9];
  __shared__ float bb1, bb2, cav;
  int bid=blockIdx.x; int b=bid>>10, c=(bid>>4)&63, sy=bid&15;
  int y0=sy*16;
  int tid=threadIdx.x;
  if(tid<9){ k1[tid]=dw1w[c*9+tid]; k2[tid]=dw2w[c*9+tid]; }
  if(tid==9)  bb1=dwb1[c];
  if(tid==10) bb2=dwb2[c];
  if(tid==11) cav=ca[b*64+c];
  const unsigned short* ip=img+(((size_t)(b*64+c))<<16);
  for(int task=tid;task<1452;task+=256){
    int r=task/66, j=task-r*66;
    int gy=y0-3+r, gx0=4*j-4;
    float4 v=make_float4(0.f,0.f,0.f,0.f);
    if((unsigned)gy<256u && j>=1 && j<=64){
      uint2 u=*(const uint2*)(ip+(gy<<8)+gx0);
      v.x=us2f(u.x&0xffff); v.y=us2f(u.x>>16); v.z=us2f(u.y&0xffff); v.w=us2f(u.y>>16);
    }
    *(float4*)&sImg[r*DWI+4*j]=v;
  }
  __syncthreads();
  for(int task=tid;task<1300;task+=256){
    int r=task/65, g=task-r*65;
    int ty=y0-2+r, tc0=4*g-2;
    float t[4]={bb1,bb1,bb1,bb1};
    #pragma unroll
    for(int dy=0;dy<3;dy++){
      float4 A0=*(const float4*)&sImg[(r+dy)*DWI+4*g];
      float4 A1=*(const float4*)&sImg[(r+dy)*DWI+4*g+4];
      float F[8]={A0.x,A0.y,A0.z,A0.w,A1.x,A1.y,A1.z,A1.w};
      #pragma unroll
      for(int dx=0;dx<3;dx++){
        float kk=k1[dy*3+dx];
        #pragma unroll
        for(int e=0;e<4;e++) t[e]+=F[1+e+dx]*kk;
      }
    }
    float4 res;
    bool rowok=((unsigned)ty<256u);
    #pragma unroll
    for(int e=0;e<4;e++){
      int tc=tc0+e;
      ((float*)&res)[e]= (rowok && (unsigned)tc<256u)? t[e] : 0.f;
    }
    *(float4*)&sTmp[r*DWI+4*g]=res;
  }
  __syncthreads();
  int q=tid&63, rr=tid>>6;
  unsigned short* op=outb+(((size_t)(b*64+c))<<16);
  #pragma unroll
  for(int l4=0;l4<4;l4++){
    int ly=rr*4+l4;
    float cs[4]={bb2,bb2,bb2,bb2};
    #pragma unroll
    for(int dy=0;dy<3;dy++){
      int r=ly+2*dy;
      float4 T0=*(const float4*)&sTmp[r*DWI+4*q];
      float4 T1=*(const float4*)&sTmp[r*DWI+4*q+4];
      float T[8]={T0.x,T0.y,T0.z,T0.w,T1.x,T1.y,T1.z,T1.w};
      #pragma unroll
      for(int dx=0;dx<3;dx++){
        float kk=k2[dy*3+dx];
        #pragma unroll
        for(int e=0;e<4;e++) cs[e]+=T[e+2*dx]*kk;
      }
    }
    float4 C=*(const float4*)&sImg[(ly+3)*DWI+4*q+4];
    float o0=geluf(cs[0])*cav+C.x;
    float o1=geluf(cs[1])*cav+C.y;
    float o2=geluf(cs[2])*cav+C.z;
    float o3=geluf(cs[3])*cav+C.w;
    uint2 u; u.x=pack2(o0,o1); u.y=pack2(o2,o3);
    *(uint2*)(op+((y0+ly)<<8)+4*q)=u;
  }
}

// ---------------- K_FDW v2: ffn depthwise (E bf16) + gelu gate, 4-col groups ----------------
#define FEI 264
__global__ __launch_bounds__(256) void k_ffn_dw_t(const unsigned short* __restrict__ E,
    const float* __restrict__ dwf, unsigned short* __restrict__ g){
  __shared__ unsigned short sE1[18*FEI];
  __shared__ unsigned short sE2[18*FEI];
  __shared__ float k1[9], k2[9];
  int bid=blockIdx.x; int b=bid>>10, c=(bid>>4)&63, sy=bid&15;
  int y0=sy*16;
  int tid=threadIdx.x;
  if(tid<9){ k1[tid]=dwf[c*9+tid]; k2[tid]=dwf[(64+c)*9+tid]; }
  const unsigned short* p1=E+(((size_t)(b*128+c))<<16);
  const unsigned short* p2=E+(((size_t)(b*128+64+c))<<16);
  for(int task=tid;task<1188;task+=256){
    int r=task/66, j=task-r*66;
    int gy=y0-1+r, gx0=4*j-4;
    uint2 u1=make_uint2(0,0), u2=make_uint2(0,0);
    if((unsigned)gy<256u && j>=1 && j<=64){
      u1=*(const uint2*)(p1+(gy<<8)+gx0);
      u2=*(const uint2*)(p2+(gy<<8)+gx0);
    }
    *(uint2*)&sE1[r*FEI+4*j]=u1;
    *(uint2*)&sE2[r*FEI+4*j]=u2;
  }
  __syncthreads();
  int q=tid&63, rr=tid>>6;
  unsigned short* op=g+(((size_t)(b*64+c))<<16);
  #pragma unroll
  for(int l4=0;l4<4;l4++){
    int ly=rr*4+l4;
    float a1[4]={0.f,0.f,0.f,0.f}, a2[4]={0.f,0.f,0.f,0.f};
    #pragma unroll
    for(int dy=0;dy<3;dy++){
      int r=ly+dy;
      unsigned w0=*(const unsigned*)&sE1[r*FEI+4*q+2];
      uint2   w1=*(const uint2*)  &sE1[r*FEI+4*q+4];
      unsigned w2=*(const unsigned*)&sE1[r*FEI+4*q+8];
      float GA[6]={us2f(w0>>16),us2f(w1.x&0xffff),us2f(w1.x>>16),us2f(w1.y&0xffff),us2f(w1.y>>16),us2f(w2&0xffff)};
      unsigned v0=*(const unsigned*)&sE2[r*FEI+4*q+2];
      uint2   v1=*(const uint2*)  &sE2[r*FEI+4*q+4];
      unsigned v2=*(const unsigned*)&sE2[r*FEI+4*q+8];
      float GB[6]={us2f(v0>>16),us2f(v1.x&0xffff),us2f(v1.x>>16),us2f(v1.y&0xffff),us2f(v1.y>>16),us2f(v2&0xffff)};
      #pragma unroll
      for(int dx=0;dx<3;dx++){
        float ka=k1[dy*3+dx], kb=k2[dy*3+dx];
        #pragma unroll
        for(int e=0;e<4;e++){
          a1[e]+=GA[e+dx]*ka;
          a2[e]+=GB[e+dx]*kb;
        }
      }
    }
    float o0=geluf(a1[0])*a2[0];
    float o1=geluf(a1[1])*a2[1];
    float o2=geluf(a1[2])*a2[2];
    float o3=geluf(a1[3])*a2[3];
    uint2 u; u.x=pack2(o0,o1); u.y=pack2(o2,o3);
    *(uint2*)(op+((y0+ly)<<8)+4*q)=u;
  }
}

extern "C" void kernel_launch(void* const* d_in, const int* in_sizes, int n_in,
                              void* d_out, int out_size, void* d_ws, size_t ws_size,
                              hipStream_t stream){
  (void)in_sizes; (void)n_in; (void)out_size; (void)ws_size;
  const void* x  = d_in[0];
  const void* Wm1= d_in[23];
  const void* Wm2= d_in[25];

  char* ws=(char*)d_ws;
  unsigned short* E=(unsigned short*)(ws);
  unsigned short* img=(unsigned short*)(ws+67108864);
  unsigned short* x1b=(unsigned short*)(ws+67108864);
  unsigned short* xwb=(unsigned short*)(ws+134217728);
  unsigned short* outb=(unsigned short*)(ws+134217728);
  unsigned short* gbuf=(unsigned short*)(ws+134217728);
  unsigned short* vw =(unsigned short*)(ws+230686720);
  char* sm = ws+201326592;
  float* x_    =(float*)(sm);              // 16 MB
  unsigned short* sa_w=(unsigned short*)(sm+16777216); // 0.5 MB
  float* xm    =(float*)(sm+17825792);     // 1 MB
  float* var   =(float*)(sm+18874368);     // 16 KB
  float* mbin  =(float*)(sm+18890752);     // 16 KB
  float* h0    =(float*)(sm+18907136);     // 8 KB
  float* h1    =(float*)(sm+18915328);     // 8 KB
  float* m0    =(float*)(sm+18923520);     // 16 KB
  float* m1    =(float*)(sm+18939904);     // 16 KB
  float* capart=(float*)(sm+18956288);     // 64 KB
  float* ca    =(float*)(sm+19021824);     // 1 KB
  int*   flag  =(int*)  (sm+19022848);     // 4 B
  float* wbuf  =(float*)(sm+19023872);     // ~161 KB
  float* m0T   =(float*)(sm+19216384);     // 16 KB
  float* m1T   =(float*)(sm+19232768);     // 16 KB
  short* Wob   =(short*)(sm+19249152);     // 8 KB
  short* Wfib  =(short*)(sm+19257344);     // 16 KB
  short* Wfob  =(short*)(sm+19273728);     // 8 KB
  short* Wvb   =(short*)(sm+19281920);     // 8 KB
  float* WaC   =(float*)(sm+19290112);     // 4 KB
  float* WbC   =(float*)(sm+19294208);     // 4 KB
  float* baC   =(float*)(sm+19298304);     // 64 B
  float* bbC   =(float*)(sm+19298560);     // 64 B
  short* MtB   =(short*)(sm+19298816);     // 8 KB
  float* cvecD =(float*)(sm+19307008);     // 256 B
  float* cconstD=(float*)(sm+19307264);    // 4 B

  static const int din_idx[31]={5,6,7,8,9,10,11,12,13,14,15,16,17,18,19,20,21,22,24,26,27,28,29,30,31,32,33,1,2,3,4};
  static const int szs[31]  ={4096,64,4096,64,4096,64,576,64,576,64,4096,64,1024,16,1024,16,16,16,2048,4096,1024,64,144,1,8192,1152,4096,64,64,64,64};
  CvtArgs ca_args;
  int off=0;
  int offs[31];
  for(int t=0;t<31;t++){
    ca_args.src[t]=d_in[din_idx[t]];
    ca_args.sz[t]=szs[t];
    ca_args.off[t]=off;
    offs[t]=off;
    off+=szs[t];
  }
  const float* Wv  =wbuf+offs[0];  const float* bv  =wbuf+offs[1];
  const float* Wq  =wbuf+offs[2];  const float* bq  =wbuf+offs[3];
  const float* Wk  =wbuf+offs[4];  const float* bk  =wbuf+offs[5];
  const float* dw1 =wbuf+offs[6];  const float* dwb1=wbuf+offs[7];
  const float* dw2 =wbuf+offs[8];  const float* dwb2=wbuf+offs[9];
  const float* Wo  =wbuf+offs[10]; const float* bo  =wbuf+offs[11];
  const float* W_in=wbuf+offs[12]; const float* b_in=wbuf+offs[13];
  const float* Wc  =wbuf+offs[14]; const float* bc  =wbuf+offs[15];
  const float* lnw =wbuf+offs[16]; const float* lnb =wbuf+offs[17];
  const float* bm1 =wbuf+offs[18]; const float* bm2 =wbuf+offs[19];
  const float* Wca =wbuf+offs[20]; const float* bca =wbuf+offs[21];
  const float* Wsa =wbuf+offs[22]; const float* bsa =wbuf+offs[23];
  const float* Wfi =wbuf+offs[24]; const float* dwf =wbuf+offs[25];
  const float* Wfo =wbuf+offs[26];
  const float* wn1 =wbuf+offs[27]; const float* bn1 =wbuf+offs[28];
  const float* wn2 =wbuf+offs[29]; const float* bn2 =wbuf+offs[30];

  hipLaunchKernelGGL(k_cvt,      dim3(31),     dim3(256), 0, stream, ca_args, x, flag, wbuf);
  hipLaunchKernelGGL(k_prep,     dim3(49),     dim3(256), 0, stream, Wo, Wfi, Wfo, Wv, Wq, Wk, bq, bk,
                     W_in, b_in, Wc, bc, bv, Wob, Wfib, Wfob, Wvb, MtB, cvecD, cconstD, WaC, baC, WbC, bbC);
  hipLaunchKernelGGL(k_route,    dim3(512),    dim3(256), 0, stream, x, flag, WaC, baC, WbC, bbC, lnw, lnb, x_, xm, capart);
  hipLaunchKernelGGL(k_sa,       dim3(1024),   dim3(256), 0, stream, x_, Wsa, bsa, sa_w);
  hipLaunchKernelGGL(k_varhvec,  dim3(1536),   dim3(256), 0, stream, xm, var, Wm1, bm1, h0, h1, flag);
  hipLaunchKernelGGL(k_rankmaskca,dim3(1044),  dim3(256), 0, stream, var, mbin, Wm2, bm2, h0, h1,
                     m0, m1, m0T, m1T, capart, Wca, bca, ca, flag);
  hipLaunchKernelGGL(k_convv_mf, dim3(4096),   dim3(256), 0, stream, x, flag, Wvb, bv, mbin, m0T, m1T, vw, xwb);
  hipLaunchKernelGGL(k_attn_mfma,dim3(4096),   dim3(256), 0, stream, xwb, vw, sa_w, mbin, m0T, m1T, MtB, cvecD, cconstD, img);
  hipLaunchKernelGGL(k_dwfuse,   dim3(4096),   dim3(256), 0, stream, img, dw1, dwb1, dw2, dwb2, ca, outb);
  hipLaunchKernelGGL(k_gemm_lnfi,dim3(4096),   dim3(256), 0, stream, outb, Wob, bo, x, wn1, bn1, x1b, Wfib, E, flag);
  hipLaunchKernelGGL(k_ffn_dw_t, dim3(4096),   dim3(256), 0, stream, E, dwf, gbuf);
  hipLaunchKernelGGL(k_gemm_ln,  dim3(4096),   dim3(256), 0, stream, gbuf, Wfob, wbuf, 0, (const void*)x1b, wn2, bn2, d_out, flag, 2, 0);
}